// Round 14
// baseline (137.910 us; speedup 1.0000x reference)
//
#include <hip/hip_runtime.h>
#include <hip/hip_bf16.h>
#include <math.h>

#define N_NODES 100000
#define N_EDGES 1000000
#define D 64
#define N3 300000          // 3 relations x N_NODES buckets
#define BCAP 16            // bucket row = exactly one 64B line
#define BM 64              // rows per gemm block
#define AST 68             // At row stride (ushorts): 2-way bank alias (free)
#define BST 68             // Bt col stride (ushorts)
#define GEMM_BLOCKS ((N_NODES + BM - 1) / BM)   // 1563
#define FILL_BLOCKS ((N_EDGES + 255) / 256)     // 3907

typedef __attribute__((ext_vector_type(8))) short bf16x8;
typedef __attribute__((ext_vector_type(4))) float f32x4;

static __device__ __forceinline__ float bf2f(unsigned short u) {
    union { unsigned int i; float f; } c; c.i = ((unsigned int)u) << 16; return c.f;
}
static __device__ __forceinline__ float lo16(unsigned int u) { return bf2f((unsigned short)(u & 0xffffu)); }
static __device__ __forceinline__ float hi16(unsigned int u) { return bf2f((unsigned short)(u >> 16)); }
static __device__ __forceinline__ unsigned short f2bf(float f) {
    union { float f; unsigned int i; } c; c.f = f;
    unsigned int i = c.i;
    return (unsigned short)((i + 0x7FFFu + ((i >> 16) & 1u)) >> 16);  // RNE
}
static __device__ __forceinline__ unsigned int pk2(float lo, float hi) {
    union { float f; unsigned int i; } a, b; a.f = lo; b.f = hi;
    unsigned int x = (a.i + 0x7FFFu + ((a.i >> 16) & 1u)) >> 16;
    unsigned int y = (b.i + 0x7FFFu + ((b.i >> 16) & 1u)) >> 16;
    return (x & 0xffffu) | (y << 16);
}

// ---------------------------------------------------------------------------
// fill body: all relations, one edge per thread. ~48us standalone (R9); this
// is the transaction-rate floor (1M atomic-with-return + 1M random 4B stores).
// ---------------------------------------------------------------------------
static __device__ __forceinline__ void fill_body(
    const int* __restrict__ src, const int* __restrict__ dst,
    const int* __restrict__ et, int* __restrict__ cnt, int* __restrict__ bucket,
    int e)
{
    if (e >= N_EDGES) return;
    int r = et[e];
    if (r >= 3) return;
    int s = src[e], d = dst[e];
    int base = r * N_NODES + s;
    int pos = atomicAdd(&cnt[base], 1);
    if (pos < BCAP) bucket[(size_t)base * BCAP + pos] = d;
}

// ---------------------------------------------------------------------------
// gemm0 body (layer 0, A = x): LDS-LIGHT. A-fragments load DIRECTLY from x —
// lane (ln,lk) reads exactly its 8-float k-slice of row `node` (same data the
// old At row-major staging provided). Bt-only LDS (17.4KB) + no A barrier:
// gemm0 blocks slot into the fill's latency bubbles without capping it.
// ---------------------------------------------------------------------------
static __device__ __forceinline__ void gemm0_body(
    int bid, const float* __restrict__ x,
    const float* __restrict__ Wm, const float* __restrict__ Rm,
    const float* __restrict__ bias,
    unsigned short* __restrict__ Y16, unsigned short* __restrict__ P16, int nN)
{
    __shared__ unsigned short Bt[128][BST];  // 17.4 KB
    int t = threadIdx.x;
    int n0 = bid * BM;

    // ---- stage B transposed: Bt[col][k] = bf16(B[k][col])
#pragma unroll
    for (int it = 0; it < 8; ++it) {
        int idx = t + it * 256;        // 0..2047
        int col = idx & 127;
        int k0  = (idx >> 7) * 4;
        const float* srcB = (col < 64) ? (Wm + col) : (Rm + col - 64);
        ushort4 wv;
        wv.x = f2bf(srcB[(k0 + 0) * 64]);
        wv.y = f2bf(srcB[(k0 + 1) * 64]);
        wv.z = f2bf(srcB[(k0 + 2) * 64]);
        wv.w = f2bf(srcB[(k0 + 3) * 64]);
        *(ushort4*)&Bt[col][k0] = wv;
    }
    __syncthreads();

    int w  = t >> 6;
    int l  = t & 63;
    int ln = l & 15;
    int lk = l >> 4;
    int node = n0 + w * 16 + ln;

    // ---- A-fragments direct from x (f32 -> bf16)
    union { bf16x8 v; unsigned short u[8]; } af[2];
#pragma unroll
    for (int ks = 0; ks < 2; ++ks) {
        float4 a = make_float4(0.f, 0.f, 0.f, 0.f), b = a;
        if (node < nN) {
            a = *(const float4*)(x + (size_t)node * 64 + ks * 32 + lk * 8);
            b = *(const float4*)(x + (size_t)node * 64 + ks * 32 + lk * 8 + 4);
        }
        af[ks].u[0] = f2bf(a.x); af[ks].u[1] = f2bf(a.y);
        af[ks].u[2] = f2bf(a.z); af[ks].u[3] = f2bf(a.w);
        af[ks].u[4] = f2bf(b.x); af[ks].u[5] = f2bf(b.y);
        af[ks].u[6] = f2bf(b.z); af[ks].u[7] = f2bf(b.w);
    }

    f32x4 acc[8];
#pragma unroll
    for (int ct = 0; ct < 8; ++ct)
        acc[ct] = (f32x4){0.f, 0.f, 0.f, 0.f};

#pragma unroll
    for (int ct = 0; ct < 8; ++ct) {
        bf16x8 bf0 = *(const bf16x8*)&Bt[ct * 16 + ln][lk * 8];
        bf16x8 bf1 = *(const bf16x8*)&Bt[ct * 16 + ln][32 + lk * 8];
        acc[ct] = __builtin_amdgcn_mfma_f32_16x16x32_bf16(bf0, af[0].v, acc[ct], 0, 0, 0);
        acc[ct] = __builtin_amdgcn_mfma_f32_16x16x32_bf16(bf1, af[1].v, acc[ct], 0, 0, 0);
    }

    if (node < nN) {
#pragma unroll
        for (int ct = 0; ct < 8; ++ct) {
            int c0 = ct * 16 + lk * 4;
            f32x4 v = acc[ct];
            if (ct < 4) {
                uint2 u;
                u.x = pk2(v[0], v[1]);
                u.y = pk2(v[2], v[3]);
                *(uint2*)(Y16 + (size_t)node * 64 + c0) = u;
            } else {
                const float4 bv = *(const float4*)(bias + (c0 - 64));
                uint2 u;
                u.x = pk2(v[0] + bv.x, v[1] + bv.y);
                u.y = pk2(v[2] + bv.z, v[3] + bv.w);
                *(uint2*)(P16 + (size_t)node * 64 + (c0 - 64)) = u;
            }
        }
    }
}

// ---------------------------------------------------------------------------
// gemm body (layers 1,2; MFMA, swapped operands): tile [64x128] = A @ [W|root]
//   A[n] = relu(bf16(Pp[n]) + sum Yp[bucket])  (gather fused in A-stage)
// ~26us each — near the practical floor for its mixed random/coalesced ~72MB
// (R13: occupancy knob was dead; gather transactions dominate).
// ---------------------------------------------------------------------------
static __device__ __forceinline__ void gemm_body(
    int bid,
    const unsigned short* __restrict__ Pp, const unsigned short* __restrict__ Yp,
    const int* __restrict__ cnt, const int* __restrict__ bucket, int relG,
    const float* __restrict__ Wm, const float* __restrict__ Rm,
    const float* __restrict__ bias,
    unsigned short* __restrict__ Y16, unsigned short* __restrict__ P16, int nN)
{
    __shared__ unsigned short At[BM][AST];   // 8.7 KB
    __shared__ unsigned short Bt[128][BST];  // 17.4 KB
    int t = threadIdx.x;
    int n0 = bid * BM;

    // ---- stage B transposed
#pragma unroll
    for (int it = 0; it < 8; ++it) {
        int idx = t + it * 256;
        int col = idx & 127;
        int k0  = (idx >> 7) * 4;
        const float* srcB = (col < 64) ? (Wm + col) : (Rm + col - 64);
        ushort4 wv;
        wv.x = f2bf(srcB[(k0 + 0) * 64]);
        wv.y = f2bf(srcB[(k0 + 1) * 64]);
        wv.z = f2bf(srcB[(k0 + 2) * 64]);
        wv.w = f2bf(srcB[(k0 + 3) * 64]);
        *(ushort4*)&Bt[col][k0] = wv;
    }

    // ---- stage A (fused gather), bf16 rows
    {
        int gidx = t >> 4, j = t & 15, lane = t & 63, grp = lane & 48;
#pragma unroll
        for (int pass = 0; pass < 4; ++pass) {
            int rw = gidx + pass * 16;
            int node = n0 + rw;
            float4 v = make_float4(0.f, 0.f, 0.f, 0.f);
            if (node < nN) {
                ushort4 pv = *(const ushort4*)(Pp + (size_t)node * 64 + j * 4);
                v = make_float4(bf2f(pv.x), bf2f(pv.y), bf2f(pv.z), bf2f(pv.w));
                int base = relG * N_NODES + node;
                int n = cnt[base]; if (n > BCAP) n = BCAP;
                const int* brow = bucket + (size_t)base * BCAP;
                int bk0 = (j < n) ? brow[j] : 0;
                for (int k = 0; k < n; ++k) {
                    int dn = __shfl(bk0, grp | k);
                    ushort4 u = *(const ushort4*)(Yp + (size_t)dn * 64 + j * 4);
                    v.x += bf2f(u.x);
                    v.y += bf2f(u.y);
                    v.z += bf2f(u.z);
                    v.w += bf2f(u.w);
                }
                v.x = fmaxf(v.x, 0.f); v.y = fmaxf(v.y, 0.f);
                v.z = fmaxf(v.z, 0.f); v.w = fmaxf(v.w, 0.f);
            }
            ushort4 av;
            av.x = f2bf(v.x); av.y = f2bf(v.y); av.z = f2bf(v.z); av.w = f2bf(v.w);
            *(ushort4*)&At[rw][j * 4] = av;
        }
    }
    __syncthreads();

    // ---- MFMA: wave w owns nodes w*16..w*16+15, 8 col-tiles
    int w  = t >> 6;
    int l  = t & 63;
    int ln = l & 15;
    int lk = l >> 4;
    f32x4 acc[8];
#pragma unroll
    for (int ct = 0; ct < 8; ++ct)
        acc[ct] = (f32x4){0.f, 0.f, 0.f, 0.f};

    bf16x8 af[2];
#pragma unroll
    for (int ks = 0; ks < 2; ++ks)
        af[ks] = *(const bf16x8*)&At[w * 16 + ln][ks * 32 + lk * 8];

#pragma unroll
    for (int ct = 0; ct < 8; ++ct) {
        bf16x8 bf0 = *(const bf16x8*)&Bt[ct * 16 + ln][lk * 8];
        bf16x8 bf1 = *(const bf16x8*)&Bt[ct * 16 + ln][32 + lk * 8];
        acc[ct] = __builtin_amdgcn_mfma_f32_16x16x32_bf16(bf0, af[0], acc[ct], 0, 0, 0);
        acc[ct] = __builtin_amdgcn_mfma_f32_16x16x32_bf16(bf1, af[1], acc[ct], 0, 0, 0);
    }

    // ---- epilogue
    int node = n0 + w * 16 + ln;
    if (node < nN) {
#pragma unroll
        for (int ct = 0; ct < 8; ++ct) {
            int c0 = ct * 16 + lk * 4;
            f32x4 v = acc[ct];
            if (ct < 4) {
                uint2 u;
                u.x = pk2(v[0], v[1]);
                u.y = pk2(v[2], v[3]);
                *(uint2*)(Y16 + (size_t)node * 64 + c0) = u;
            } else {
                const float4 bv = *(const float4*)(bias + (c0 - 64));
                uint2 u;
                u.x = pk2(v[0] + bv.x, v[1] + bv.y);
                u.y = pk2(v[2] + bv.z, v[3] + bv.w);
                *(uint2*)(P16 + (size_t)node * 64 + (c0 - 64)) = u;
            }
        }
    }
}

// ---------------------------------------------------------------------------
// fused0: FILL blocks FIRST (blockIdx < FILL_BLOCKS) — the 48us long pole
// starts at t=0 (R13 had gemm first: fill started ~8us late -> 56us total).
// gemm0 blocks launch behind and hide in the fill's latency bubbles.
// ---------------------------------------------------------------------------
__global__ __launch_bounds__(256) void fused0_kernel(
    const float* __restrict__ x,
    const int* __restrict__ src, const int* __restrict__ dst,
    const int* __restrict__ et, int* __restrict__ cnt, int* __restrict__ bucket,
    const float* __restrict__ Wm, const float* __restrict__ Rm,
    const float* __restrict__ bias,
    unsigned short* __restrict__ Y16, unsigned short* __restrict__ P16, int nN)
{
    if (blockIdx.x < FILL_BLOCKS) {
        int e = blockIdx.x * 256 + threadIdx.x;
        fill_body(src, dst, et, cnt, bucket, e);
    } else {
        gemm0_body(blockIdx.x - FILL_BLOCKS, x, Wm, Rm, bias, Y16, P16, nN);
    }
}

// ---------------------------------------------------------------------------
// gemm_node: layers 1,2 (gather fused in A-stage)
// ---------------------------------------------------------------------------
__global__ __launch_bounds__(256) void gemm_node_kernel(
    const unsigned short* __restrict__ Pp, const unsigned short* __restrict__ Yp,
    const int* __restrict__ cnt, const int* __restrict__ bucket, int rel,
    const float* __restrict__ Wm, const float* __restrict__ Rm,
    const float* __restrict__ bias,
    unsigned short* __restrict__ Y16, unsigned short* __restrict__ P16, int nN)
{
    gemm_body(blockIdx.x, Pp, Yp, cnt, bucket, rel,
              Wm, Rm, bias, Y16, P16, nN);
}

// ---------------------------------------------------------------------------
// final (MFMA): 16 nodes/wave; row = relu(bf16 P2[n] + gather(rel2)); logits
// via swapped mfma; log_softmax with 2 shfl_xor; one float4 store per lane.
// ---------------------------------------------------------------------------
__global__ __launch_bounds__(256) void final_kernel(
    const unsigned short* __restrict__ P2, const unsigned short* __restrict__ Y2,
    const int* __restrict__ cnt, const int* __restrict__ bucket, int rel,
    const float* __restrict__ Wl, const float* __restrict__ bl,
    float* __restrict__ out, int nN)
{
    int t = threadIdx.x;
    int w = t >> 6, l = t & 63;
    int ln = l & 15, lk = l >> 4;
    int node = blockIdx.x * 64 + w * 16 + ln;

    bf16x8 wf[2];
#pragma unroll
    for (int ks = 0; ks < 2; ++ks) {
        union { bf16x8 v; unsigned short u[8]; } tmp;
#pragma unroll
        for (int i = 0; i < 8; ++i)
            tmp.u[i] = f2bf(Wl[(ks * 32 + lk * 8 + i) * 16 + ln]);
        wf[ks] = tmp.v;
    }

    float v[16];
#pragma unroll
    for (int i = 0; i < 16; ++i) v[i] = 0.f;
    if (node < nN) {
#pragma unroll
        for (int ks = 0; ks < 2; ++ks) {
            uint4 pu = *(const uint4*)(P2 + (size_t)node * 64 + ks * 32 + lk * 8);
            v[ks * 8 + 0] = lo16(pu.x); v[ks * 8 + 1] = hi16(pu.x);
            v[ks * 8 + 2] = lo16(pu.y); v[ks * 8 + 3] = hi16(pu.y);
            v[ks * 8 + 4] = lo16(pu.z); v[ks * 8 + 5] = hi16(pu.z);
            v[ks * 8 + 6] = lo16(pu.w); v[ks * 8 + 7] = hi16(pu.w);
        }
        int base = rel * N_NODES + node;
        int n = cnt[base]; if (n > BCAP) n = BCAP;
        const int* brow = bucket + (size_t)base * BCAP;
        for (int k = 0; k < n; ++k) {
            int dn = brow[k];
#pragma unroll
            for (int ks = 0; ks < 2; ++ks) {
                uint4 yu = *(const uint4*)(Y2 + (size_t)dn * 64 + ks * 32 + lk * 8);
                v[ks * 8 + 0] += lo16(yu.x); v[ks * 8 + 1] += hi16(yu.x);
                v[ks * 8 + 2] += lo16(yu.y); v[ks * 8 + 3] += hi16(yu.y);
                v[ks * 8 + 4] += lo16(yu.z); v[ks * 8 + 5] += hi16(yu.z);
                v[ks * 8 + 6] += lo16(yu.w); v[ks * 8 + 7] += hi16(yu.w);
            }
        }
#pragma unroll
        for (int i = 0; i < 16; ++i) v[i] = fmaxf(v[i], 0.f);
    }
    union { bf16x8 bv; unsigned short u[8]; } af[2];
#pragma unroll
    for (int ks = 0; ks < 2; ++ks)
#pragma unroll
        for (int i = 0; i < 8; ++i) af[ks].u[i] = f2bf(v[ks * 8 + i]);

    f32x4 acc = (f32x4){0.f, 0.f, 0.f, 0.f};
    acc = __builtin_amdgcn_mfma_f32_16x16x32_bf16(wf[0], af[0].bv, acc, 0, 0, 0);
    acc = __builtin_amdgcn_mfma_f32_16x16x32_bf16(wf[1], af[1].bv, acc, 0, 0, 0);

    if (node < nN) {
        float4 blv = *(const float4*)(bl + lk * 4);
        float p0 = acc[0] + blv.x, p1 = acc[1] + blv.y;
        float p2 = acc[2] + blv.z, p3 = acc[3] + blv.w;
        float mx = fmaxf(fmaxf(p0, p1), fmaxf(p2, p3));
        mx = fmaxf(mx, __shfl_xor(mx, 16));
        mx = fmaxf(mx, __shfl_xor(mx, 32));
        float s = __expf(p0 - mx) + __expf(p1 - mx) + __expf(p2 - mx) + __expf(p3 - mx);
        s += __shfl_xor(s, 16);
        s += __shfl_xor(s, 32);
        float ls = logf(s) + mx;
        float4 r = make_float4(p0 - ls, p1 - ls, p2 - ls, p3 - ls);
        *(float4*)(out + (size_t)node * 16 + lk * 4) = r;
    }
}

extern "C" void kernel_launch(void* const* d_in, const int* in_sizes, int n_in,
                              void* d_out, int out_size, void* d_ws, size_t ws_size,
                              hipStream_t stream) {
    const float* x     = (const float*)d_in[0];
    const int*   ei    = (const int*)  d_in[1];   // [2, E]
    const int*   et    = (const int*)  d_in[2];   // [E]
    const float* W1    = (const float*)d_in[3];   // [5,64,64]
    const float* root1 = (const float*)d_in[4];   // [64,64]
    const float* b1    = (const float*)d_in[5];   // [64]
    const float* W2    = (const float*)d_in[6];   // [5,64,64]
    const float* root2 = (const float*)d_in[7];   // [64,64]
    const float* b2    = (const float*)d_in[8];   // [64]
    const float* Wl    = (const float*)d_in[9];   // [64,16]
    const float* bl    = (const float*)d_in[10];  // [16]
    float* out = (float*)d_out;

    const int N = N_NODES, E = N_EDGES;
    const size_t hBytes   = (size_t)N * D * sizeof(unsigned short);           // 12.8 MB
    const size_t cntBytes = ((size_t)N3 * sizeof(int) + 255) & ~(size_t)255;  // 1.2 MB
    const size_t bktBytes = ((size_t)N3 * BCAP * sizeof(int) + 255) & ~(size_t)255; // 19.2 MB

    char* ws = (char*)d_ws;
    unsigned short* Ya = (unsigned short*)ws;                 ws += hBytes;
    unsigned short* Yb = (unsigned short*)ws;                 ws += hBytes;
    unsigned short* Pa = (unsigned short*)ws;                 ws += hBytes;
    unsigned short* Pb = (unsigned short*)ws;                 ws += hBytes;
    int* cnt    = (int*)ws;                                   ws += cntBytes;
    int* bucket = (int*)ws;                                   ws += bktBytes;

    const int* src = ei;       // edge_index[0]
    const int* dst = ei + E;   // edge_index[1]

    const int finalBlocks = (N + 63) / 64;

    // ---- counters must be zero before fill
    hipMemsetAsync(cnt, 0, (size_t)N3 * sizeof(int), stream);

    // ---- fused: full bucket fill (blocks first) + layer-0 gemm (A = x)
    fused0_kernel<<<FILL_BLOCKS + GEMM_BLOCKS, 256, 0, stream>>>(
        x, src, dst, et, cnt, bucket, W1 + 0 * D * D, root1, b1, Ya, Pa, N);

    // ---- layer 1: A = relu(Pa + gather(rel0, Ya)); W2[1]/root2/b2 -> (Yb, Pb)
    gemm_node_kernel<<<GEMM_BLOCKS, 256, 0, stream>>>(
        Pa, Ya, cnt, bucket, 0, W2 + 1 * D * D, root2, b2, Yb, Pb, N);

    // ---- layer 2: A = relu(Pb + gather(rel1, Yb)); W2[2]/root2/b2 -> (Ya, Pa)
    gemm_node_kernel<<<GEMM_BLOCKS, 256, 0, stream>>>(
        Pb, Yb, cnt, bucket, 1, W2 + 2 * D * D, root2, b2, Ya, Pa, N);

    // ---- final: relu(Pa + gather(rel2, Ya)) @ Wl + bl -> log_softmax
    final_kernel<<<finalBlocks, 256, 0, stream>>>(
        Pa, Ya, cnt, bucket, 2, Wl, bl, out, N);
}

// Round 15
// 118.850 us; speedup vs baseline: 1.1604x; 1.1604x over previous
//
#include <hip/hip_runtime.h>
#include <hip/hip_bf16.h>
#include <math.h>

#define N_NODES 100000
#define N_EDGES 1000000
#define D 64
#define N3 300000          // 3 relations x N_NODES buckets
#define BCAP 16            // bucket row = exactly one 64B line
#define BM 128             // rows per gemm block (R12 config — best measured)
#define AST 72             // At row stride (ushorts)
#define BST 72             // Bt col stride (ushorts)
#define GEMM_BLOCKS ((N_NODES + BM - 1) / BM)     // 782
#define FILL_BLOCKS ((N_EDGES + 1023) / 1024)     // 977 (4 edges/thread)

typedef __attribute__((ext_vector_type(8))) short bf16x8;
typedef __attribute__((ext_vector_type(4))) float f32x4;

static __device__ __forceinline__ float bf2f(unsigned short u) {
    union { unsigned int i; float f; } c; c.i = ((unsigned int)u) << 16; return c.f;
}
static __device__ __forceinline__ float lo16(unsigned int u) { return bf2f((unsigned short)(u & 0xffffu)); }
static __device__ __forceinline__ float hi16(unsigned int u) { return bf2f((unsigned short)(u >> 16)); }
static __device__ __forceinline__ unsigned short f2bf(float f) {
    union { float f; unsigned int i; } c; c.f = f;
    unsigned int i = c.i;
    return (unsigned short)((i + 0x7FFFu + ((i >> 16) & 1u)) >> 16);  // RNE
}
static __device__ __forceinline__ unsigned int pk2(float lo, float hi) {
    return (unsigned int)f2bf(lo) | ((unsigned int)f2bf(hi) << 16);
}

// ---------------------------------------------------------------------------
// fill body, 4 edges per thread (int4 loads). R14 post-mortem: one edge per
// thread = one dependent chain (et -> src/dst -> atomic-return -> store) per
// thread, issue/latency-bound at <1% VALU. Four INDEPENDENT chains per thread
// quadruple memory-level parallelism at identical transaction count.
// ---------------------------------------------------------------------------
static __device__ __forceinline__ void fill_body4(
    const int* __restrict__ src, const int* __restrict__ dst,
    const int* __restrict__ et, int* __restrict__ cnt, int* __restrict__ bucket,
    int e0)
{
    if (e0 >= N_EDGES) return;   // N_EDGES % 4 == 0, so e0+3 < N_EDGES too
    int4 t4 = *(const int4*)(et + e0);
    int4 s4 = *(const int4*)(src + e0);
    int4 d4 = *(const int4*)(dst + e0);
    int t[4] = { t4.x, t4.y, t4.z, t4.w };
    int s[4] = { s4.x, s4.y, s4.z, s4.w };
    int d[4] = { d4.x, d4.y, d4.z, d4.w };
#pragma unroll
    for (int i = 0; i < 4; ++i) {
        if (t[i] < 3) {
            int base = t[i] * N_NODES + s[i];
            int pos = atomicAdd(&cnt[base], 1);
            if (pos < BCAP) bucket[(size_t)base * BCAP + pos] = d[i];
        }
    }
}

// ---------------------------------------------------------------------------
// gemm body (MFMA, swapped operands): tile [BM x 128] = A[BMx64] @ [W|root].
//   A[n] = x[n]                                (relG < 0, f32 input)
//   A[n] = relu(bf16(Pp[n]) + sum Yp[bucket])  (relG >= 0, gather fused)
// Outputs bf16 Y (cols 0..63) and bf16 P (cols 64..127, +bias).
// Swapped mfma(bf, af): lane&15 = node, reg-quad = 4 consecutive output cols
// -> uint2 epilogue stores. Frag layouts m89-verified (R9-R14 passed).
// ---------------------------------------------------------------------------
static __device__ __forceinline__ void gemm_body(
    int bid,
    const float* __restrict__ Hin, const unsigned short* __restrict__ Pp,
    const unsigned short* __restrict__ Yp,
    const int* __restrict__ cnt, const int* __restrict__ bucket, int relG,
    const float* __restrict__ Wm, const float* __restrict__ Rm,
    const float* __restrict__ bias,
    unsigned short* __restrict__ Y16, unsigned short* __restrict__ P16, int nN)
{
    __shared__ unsigned short At[BM][AST];   // A rows, bf16 [row][k]
    __shared__ unsigned short Bt[128][BST];  // B cols, bf16 [col][k]
    int t = threadIdx.x;
    int n0 = bid * BM;

    // ---- stage B transposed: Bt[col][k] = bf16(B[k][col])
#pragma unroll
    for (int it = 0; it < 8; ++it) {
        int idx = t + it * 256;        // 0..2047
        int col = idx & 127;
        int k0  = (idx >> 7) * 4;
        const float* srcB = (col < 64) ? (Wm + col) : (Rm + col - 64);
        ushort4 wv;
        wv.x = f2bf(srcB[(k0 + 0) * 64]);
        wv.y = f2bf(srcB[(k0 + 1) * 64]);
        wv.z = f2bf(srcB[(k0 + 2) * 64]);
        wv.w = f2bf(srcB[(k0 + 3) * 64]);
        *(ushort4*)&Bt[col][k0] = wv;
    }

    // ---- stage A (fused gather), bf16 rows
    {
        int gidx = t >> 4, j = t & 15, lane = t & 63, grp = lane & 48;
#pragma unroll
        for (int pass = 0; pass < 8; ++pass) {
            int rw = gidx + pass * 16;
            int node = n0 + rw;
            float4 v = make_float4(0.f, 0.f, 0.f, 0.f);
            if (node < nN) {
                if (relG < 0) {
                    v = *(const float4*)(Hin + (size_t)node * 64 + j * 4);
                } else {
                    ushort4 pv = *(const ushort4*)(Pp + (size_t)node * 64 + j * 4);
                    v = make_float4(bf2f(pv.x), bf2f(pv.y), bf2f(pv.z), bf2f(pv.w));
                    int base = relG * N_NODES + node;
                    int n = cnt[base]; if (n > BCAP) n = BCAP;
                    const int* brow = bucket + (size_t)base * BCAP;
                    int bk0 = (j < n) ? brow[j] : 0;
                    for (int k = 0; k < n; ++k) {
                        int dn = __shfl(bk0, grp | k);
                        ushort4 u = *(const ushort4*)(Yp + (size_t)dn * 64 + j * 4);
                        v.x += bf2f(u.x);
                        v.y += bf2f(u.y);
                        v.z += bf2f(u.z);
                        v.w += bf2f(u.w);
                    }
                    v.x = fmaxf(v.x, 0.f); v.y = fmaxf(v.y, 0.f);
                    v.z = fmaxf(v.z, 0.f); v.w = fmaxf(v.w, 0.f);
                }
            }
            ushort4 av;
            av.x = f2bf(v.x); av.y = f2bf(v.y); av.z = f2bf(v.z); av.w = f2bf(v.w);
            *(ushort4*)&At[rw][j * 4] = av;
        }
    }
    __syncthreads();

    // ---- MFMA main: wave w owns nodes w*32..w*32+31 (2 node-tiles) x 8 col-tiles
    int w  = t >> 6;
    int l  = t & 63;
    int ln = l & 15;
    int lk = l >> 4;
    f32x4 acc[2][8];
#pragma unroll
    for (int nt = 0; nt < 2; ++nt)
#pragma unroll
        for (int ct = 0; ct < 8; ++ct)
            acc[nt][ct] = (f32x4){0.f, 0.f, 0.f, 0.f};

    bf16x8 af[2][2];
#pragma unroll
    for (int nt = 0; nt < 2; ++nt)
#pragma unroll
        for (int ks = 0; ks < 2; ++ks)
            af[nt][ks] = *(const bf16x8*)&At[w * 32 + nt * 16 + ln][ks * 32 + lk * 8];

#pragma unroll
    for (int ct = 0; ct < 8; ++ct) {
        bf16x8 bf0 = *(const bf16x8*)&Bt[ct * 16 + ln][lk * 8];
        bf16x8 bf1 = *(const bf16x8*)&Bt[ct * 16 + ln][32 + lk * 8];
#pragma unroll
        for (int nt = 0; nt < 2; ++nt) {
            acc[nt][ct] = __builtin_amdgcn_mfma_f32_16x16x32_bf16(bf0, af[nt][0], acc[nt][ct], 0, 0, 0);
            acc[nt][ct] = __builtin_amdgcn_mfma_f32_16x16x32_bf16(bf1, af[nt][1], acc[nt][ct], 0, 0, 0);
        }
    }

    // ---- epilogue: lane holds node=ln, 4 consecutive cols per reg-quad; bf16 both halves
#pragma unroll
    for (int ct = 0; ct < 8; ++ct) {
        int c0 = ct * 16 + lk * 4;
#pragma unroll
        for (int nt = 0; nt < 2; ++nt) {
            int node = n0 + w * 32 + nt * 16 + ln;
            if (node >= nN) continue;
            f32x4 v = acc[nt][ct];
            if (ct < 4) {
                uint2 u;
                u.x = pk2(v[0], v[1]);
                u.y = pk2(v[2], v[3]);
                *(uint2*)(Y16 + (size_t)node * 64 + c0) = u;
            } else {
                const float4 bv = *(const float4*)(bias + (c0 - 64));
                uint2 u;
                u.x = pk2(v[0] + bv.x, v[1] + bv.y);
                u.y = pk2(v[2] + bv.z, v[3] + bv.w);
                *(uint2*)(P16 + (size_t)node * 64 + (c0 - 64)) = u;
            }
        }
    }
}

// ---------------------------------------------------------------------------
// fused0: blocks [0, GEMM_BLOCKS) run layer-0 gemm (A = x); remaining blocks
// run the vectorized bucket fill (4 edges/thread). R12 ordering (gemm first)
// measured best across R12-R14 ordering variants.
// ---------------------------------------------------------------------------
__global__ __launch_bounds__(256) void fused0_kernel(
    const float* __restrict__ x,
    const int* __restrict__ src, const int* __restrict__ dst,
    const int* __restrict__ et, int* __restrict__ cnt, int* __restrict__ bucket,
    const float* __restrict__ Wm, const float* __restrict__ Rm,
    const float* __restrict__ bias,
    unsigned short* __restrict__ Y16, unsigned short* __restrict__ P16, int nN)
{
    if (blockIdx.x < GEMM_BLOCKS) {
        gemm_body(blockIdx.x, x, nullptr, nullptr, nullptr, nullptr, -1,
                  Wm, Rm, bias, Y16, P16, nN);
    } else {
        int e0 = ((blockIdx.x - GEMM_BLOCKS) * 256 + threadIdx.x) * 4;
        fill_body4(src, dst, et, cnt, bucket, e0);
    }
}

// ---------------------------------------------------------------------------
// gemm_node: layers 1,2 (gather fused in A-stage)
// ---------------------------------------------------------------------------
__global__ __launch_bounds__(256) void gemm_node_kernel(
    const unsigned short* __restrict__ Pp, const unsigned short* __restrict__ Yp,
    const int* __restrict__ cnt, const int* __restrict__ bucket, int rel,
    const float* __restrict__ Wm, const float* __restrict__ Rm,
    const float* __restrict__ bias,
    unsigned short* __restrict__ Y16, unsigned short* __restrict__ P16, int nN)
{
    gemm_body(blockIdx.x, nullptr, Pp, Yp, cnt, bucket, rel,
              Wm, Rm, bias, Y16, P16, nN);
}

// ---------------------------------------------------------------------------
// final (MFMA): 16 nodes/wave; row = relu(bf16 P2[n] + gather(rel2)); logits
// via swapped mfma; log_softmax with 2 shfl_xor; one float4 store per lane.
// ---------------------------------------------------------------------------
__global__ __launch_bounds__(256) void final_kernel(
    const unsigned short* __restrict__ P2, const unsigned short* __restrict__ Y2,
    const int* __restrict__ cnt, const int* __restrict__ bucket, int rel,
    const float* __restrict__ Wl, const float* __restrict__ bl,
    float* __restrict__ out, int nN)
{
    int t = threadIdx.x;
    int w = t >> 6, l = t & 63;
    int ln = l & 15, lk = l >> 4;
    int node = blockIdx.x * 64 + w * 16 + ln;

    bf16x8 wf[2];
#pragma unroll
    for (int ks = 0; ks < 2; ++ks) {
        union { bf16x8 v; unsigned short u[8]; } tmp;
#pragma unroll
        for (int i = 0; i < 8; ++i)
            tmp.u[i] = f2bf(Wl[(ks * 32 + lk * 8 + i) * 16 + ln]);
        wf[ks] = tmp.v;
    }

    float v[16];
#pragma unroll
    for (int i = 0; i < 16; ++i) v[i] = 0.f;
    if (node < nN) {
#pragma unroll
        for (int ks = 0; ks < 2; ++ks) {
            uint4 pu = *(const uint4*)(P2 + (size_t)node * 64 + ks * 32 + lk * 8);
            v[ks * 8 + 0] = lo16(pu.x); v[ks * 8 + 1] = hi16(pu.x);
            v[ks * 8 + 2] = lo16(pu.y); v[ks * 8 + 3] = hi16(pu.y);
            v[ks * 8 + 4] = lo16(pu.z); v[ks * 8 + 5] = hi16(pu.z);
            v[ks * 8 + 6] = lo16(pu.w); v[ks * 8 + 7] = hi16(pu.w);
        }
        int base = rel * N_NODES + node;
        int n = cnt[base]; if (n > BCAP) n = BCAP;
        const int* brow = bucket + (size_t)base * BCAP;
        for (int k = 0; k < n; ++k) {
            int dn = brow[k];
#pragma unroll
            for (int ks = 0; ks < 2; ++ks) {
                uint4 yu = *(const uint4*)(Y2 + (size_t)dn * 64 + ks * 32 + lk * 8);
                v[ks * 8 + 0] += lo16(yu.x); v[ks * 8 + 1] += hi16(yu.x);
                v[ks * 8 + 2] += lo16(yu.y); v[ks * 8 + 3] += hi16(yu.y);
                v[ks * 8 + 4] += lo16(yu.z); v[ks * 8 + 5] += hi16(yu.z);
                v[ks * 8 + 6] += lo16(yu.w); v[ks * 8 + 7] += hi16(yu.w);
            }
        }
#pragma unroll
        for (int i = 0; i < 16; ++i) v[i] = fmaxf(v[i], 0.f);
    }
    union { bf16x8 bv; unsigned short u[8]; } af[2];
#pragma unroll
    for (int ks = 0; ks < 2; ++ks)
#pragma unroll
        for (int i = 0; i < 8; ++i) af[ks].u[i] = f2bf(v[ks * 8 + i]);

    f32x4 acc = (f32x4){0.f, 0.f, 0.f, 0.f};
    acc = __builtin_amdgcn_mfma_f32_16x16x32_bf16(wf[0], af[0].bv, acc, 0, 0, 0);
    acc = __builtin_amdgcn_mfma_f32_16x16x32_bf16(wf[1], af[1].bv, acc, 0, 0, 0);

    if (node < nN) {
        float4 blv = *(const float4*)(bl + lk * 4);
        float p0 = acc[0] + blv.x, p1 = acc[1] + blv.y;
        float p2 = acc[2] + blv.z, p3 = acc[3] + blv.w;
        float mx = fmaxf(fmaxf(p0, p1), fmaxf(p2, p3));
        mx = fmaxf(mx, __shfl_xor(mx, 16));
        mx = fmaxf(mx, __shfl_xor(mx, 32));
        float s = __expf(p0 - mx) + __expf(p1 - mx) + __expf(p2 - mx) + __expf(p3 - mx);
        s += __shfl_xor(s, 16);
        s += __shfl_xor(s, 32);
        float ls = logf(s) + mx;
        float4 r = make_float4(p0 - ls, p1 - ls, p2 - ls, p3 - ls);
        *(float4*)(out + (size_t)node * 16 + lk * 4) = r;
    }
}

extern "C" void kernel_launch(void* const* d_in, const int* in_sizes, int n_in,
                              void* d_out, int out_size, void* d_ws, size_t ws_size,
                              hipStream_t stream) {
    const float* x     = (const float*)d_in[0];
    const int*   ei    = (const int*)  d_in[1];   // [2, E]
    const int*   et    = (const int*)  d_in[2];   // [E]
    const float* W1    = (const float*)d_in[3];   // [5,64,64]
    const float* root1 = (const float*)d_in[4];   // [64,64]
    const float* b1    = (const float*)d_in[5];   // [64]
    const float* W2    = (const float*)d_in[6];   // [5,64,64]
    const float* root2 = (const float*)d_in[7];   // [64,64]
    const float* b2    = (const float*)d_in[8];   // [64]
    const float* Wl    = (const float*)d_in[9];   // [64,16]
    const float* bl    = (const float*)d_in[10];  // [16]
    float* out = (float*)d_out;

    const int N = N_NODES, E = N_EDGES;
    const size_t hBytes   = (size_t)N * D * sizeof(unsigned short);           // 12.8 MB
    const size_t cntBytes = ((size_t)N3 * sizeof(int) + 255) & ~(size_t)255;  // 1.2 MB
    const size_t bktBytes = ((size_t)N3 * BCAP * sizeof(int) + 255) & ~(size_t)255; // 19.2 MB

    char* ws = (char*)d_ws;
    unsigned short* Ya = (unsigned short*)ws;                 ws += hBytes;
    unsigned short* Yb = (unsigned short*)ws;                 ws += hBytes;
    unsigned short* Pa = (unsigned short*)ws;                 ws += hBytes;
    unsigned short* Pb = (unsigned short*)ws;                 ws += hBytes;
    int* cnt    = (int*)ws;                                   ws += cntBytes;
    int* bucket = (int*)ws;                                   ws += bktBytes;

    const int* src = ei;       // edge_index[0]
    const int* dst = ei + E;   // edge_index[1]

    const int finalBlocks = (N + 63) / 64;

    // ---- counters must be zero before fill
    hipMemsetAsync(cnt, 0, (size_t)N3 * sizeof(int), stream);

    // ---- fused: layer-0 gemm (A = x) + vectorized bucket fill
    fused0_kernel<<<GEMM_BLOCKS + FILL_BLOCKS, 256, 0, stream>>>(
        x, src, dst, et, cnt, bucket, W1 + 0 * D * D, root1, b1, Ya, Pa, N);

    // ---- layer 1: A = relu(Pa + gather(rel0, Ya)); W2[1]/root2/b2 -> (Yb, Pb)
    gemm_node_kernel<<<GEMM_BLOCKS, 256, 0, stream>>>(
        Pa, Ya, cnt, bucket, 0, W2 + 1 * D * D, root2, b2, Yb, Pb, N);

    // ---- layer 2: A = relu(Pb + gather(rel1, Yb)); W2[2]/root2/b2 -> (Ya, Pa)
    gemm_node_kernel<<<GEMM_BLOCKS, 256, 0, stream>>>(
        Pb, Yb, cnt, bucket, 1, W2 + 2 * D * D, root2, b2, Ya, Pa, N);

    // ---- final: relu(Pa + gather(rel2, Ya)) @ Wl + bl -> log_softmax
    final_kernel<<<finalBlocks, 256, 0, stream>>>(
        Pa, Ya, cnt, bucket, 2, Wl, bl, out, N);
}

// Round 16
// 112.409 us; speedup vs baseline: 1.2269x; 1.0573x over previous
//
#include <hip/hip_runtime.h>
#include <hip/hip_bf16.h>
#include <math.h>

#define N_NODES 100000
#define N_EDGES 1000000
#define D 64
#define N3 300000          // 3 relations x N_NODES buckets
#define BCAP 16            // bucket row = exactly one 64B line
#define BM 128             // rows per gemm block (R12/R15 config — best measured)
#define AST 72             // At row stride (ushorts)
#define BST 72             // Bt col stride (ushorts)
#define GEMM_BLOCKS ((N_NODES + BM - 1) / BM)     // 782
#define FILL_BLOCKS ((N_EDGES + 1023) / 1024)     // 977 (4 edges/thread)

typedef __attribute__((ext_vector_type(8))) short bf16x8;
typedef __attribute__((ext_vector_type(4))) float f32x4;

static __device__ __forceinline__ float bf2f(unsigned short u) {
    union { unsigned int i; float f; } c; c.i = ((unsigned int)u) << 16; return c.f;
}
static __device__ __forceinline__ float lo16(unsigned int u) { return bf2f((unsigned short)(u & 0xffffu)); }
static __device__ __forceinline__ float hi16(unsigned int u) { return bf2f((unsigned short)(u >> 16)); }
static __device__ __forceinline__ unsigned short f2bf(float f) {
    union { float f; unsigned int i; } c; c.f = f;
    unsigned int i = c.i;
    return (unsigned short)((i + 0x7FFFu + ((i >> 16) & 1u)) >> 16);  // RNE
}
static __device__ __forceinline__ unsigned int pk2(float lo, float hi) {
    return (unsigned int)f2bf(lo) | ((unsigned int)f2bf(hi) << 16);
}

// ---------------------------------------------------------------------------
// fill body, 4 edges per thread (int4 loads): 4 independent atomic+store
// chains in flight per thread (R15: fused0 58.9 -> 43.4us).
// ---------------------------------------------------------------------------
static __device__ __forceinline__ void fill_body4(
    const int* __restrict__ src, const int* __restrict__ dst,
    const int* __restrict__ et, int* __restrict__ cnt, int* __restrict__ bucket,
    int e0)
{
    if (e0 >= N_EDGES) return;   // N_EDGES % 4 == 0
    int4 t4 = *(const int4*)(et + e0);
    int4 s4 = *(const int4*)(src + e0);
    int4 d4 = *(const int4*)(dst + e0);
    int t[4] = { t4.x, t4.y, t4.z, t4.w };
    int s[4] = { s4.x, s4.y, s4.z, s4.w };
    int d[4] = { d4.x, d4.y, d4.z, d4.w };
#pragma unroll
    for (int i = 0; i < 4; ++i) {
        if (t[i] < 3) {
            int base = t[i] * N_NODES + s[i];
            int pos = atomicAdd(&cnt[base], 1);
            if (pos < BCAP) bucket[(size_t)base * BCAP + pos] = d[i];
        }
    }
}

// ---------------------------------------------------------------------------
// gemm body (MFMA, swapped operands): tile [BM x 128] = A[BMx64] @ [W|root].
//   A[n] = x[n]                                (relG < 0, f32 input)
//   A[n] = relu(bf16(Pp[n]) + sum Yp[bucket])  (relG >= 0, gather fused)
// R16: gather loop BATCHED 4-deep — the dynamic-trip loop serialized one
// ~400cy Y-row load per iteration; 4 clamped-index loads issue together
// (clamped duplicates hit the same L1 line), only the adds are predicated.
// ---------------------------------------------------------------------------
static __device__ __forceinline__ void gemm_body(
    int bid,
    const float* __restrict__ Hin, const unsigned short* __restrict__ Pp,
    const unsigned short* __restrict__ Yp,
    const int* __restrict__ cnt, const int* __restrict__ bucket, int relG,
    const float* __restrict__ Wm, const float* __restrict__ Rm,
    const float* __restrict__ bias,
    unsigned short* __restrict__ Y16, unsigned short* __restrict__ P16, int nN)
{
    __shared__ unsigned short At[BM][AST];   // A rows, bf16 [row][k]
    __shared__ unsigned short Bt[128][BST];  // B cols, bf16 [col][k]
    int t = threadIdx.x;
    int n0 = bid * BM;

    // ---- stage B transposed: Bt[col][k] = bf16(B[k][col])
#pragma unroll
    for (int it = 0; it < 8; ++it) {
        int idx = t + it * 256;        // 0..2047
        int col = idx & 127;
        int k0  = (idx >> 7) * 4;
        const float* srcB = (col < 64) ? (Wm + col) : (Rm + col - 64);
        ushort4 wv;
        wv.x = f2bf(srcB[(k0 + 0) * 64]);
        wv.y = f2bf(srcB[(k0 + 1) * 64]);
        wv.z = f2bf(srcB[(k0 + 2) * 64]);
        wv.w = f2bf(srcB[(k0 + 3) * 64]);
        *(ushort4*)&Bt[col][k0] = wv;
    }

    // ---- stage A (fused gather, 4-deep batched), bf16 rows
    {
        int gidx = t >> 4, j = t & 15, lane = t & 63, grp = lane & 48;
#pragma unroll
        for (int pass = 0; pass < 8; ++pass) {
            int rw = gidx + pass * 16;
            int node = n0 + rw;
            float4 v = make_float4(0.f, 0.f, 0.f, 0.f);
            if (node < nN) {
                if (relG < 0) {
                    v = *(const float4*)(Hin + (size_t)node * 64 + j * 4);
                } else {
                    ushort4 pv = *(const ushort4*)(Pp + (size_t)node * 64 + j * 4);
                    v = make_float4(bf2f(pv.x), bf2f(pv.y), bf2f(pv.z), bf2f(pv.w));
                    int base = relG * N_NODES + node;
                    int n = cnt[base]; if (n > BCAP) n = BCAP;
                    const int* brow = bucket + (size_t)base * BCAP;
                    int bk0 = (j < n) ? brow[j] : 0;
                    for (int k = 0; k < n; k += 4) {
                        int i1 = (k + 1 < n) ? k + 1 : k;
                        int i2 = (k + 2 < n) ? k + 2 : k;
                        int i3 = (k + 3 < n) ? k + 3 : k;
                        int dn0 = __shfl(bk0, grp | k);
                        int dn1 = __shfl(bk0, grp | i1);
                        int dn2 = __shfl(bk0, grp | i2);
                        int dn3 = __shfl(bk0, grp | i3);
                        ushort4 u0 = *(const ushort4*)(Yp + (size_t)dn0 * 64 + j * 4);
                        ushort4 u1 = *(const ushort4*)(Yp + (size_t)dn1 * 64 + j * 4);
                        ushort4 u2 = *(const ushort4*)(Yp + (size_t)dn2 * 64 + j * 4);
                        ushort4 u3 = *(const ushort4*)(Yp + (size_t)dn3 * 64 + j * 4);
                        v.x += bf2f(u0.x); v.y += bf2f(u0.y);
                        v.z += bf2f(u0.z); v.w += bf2f(u0.w);
                        if (k + 1 < n) {
                            v.x += bf2f(u1.x); v.y += bf2f(u1.y);
                            v.z += bf2f(u1.z); v.w += bf2f(u1.w);
                        }
                        if (k + 2 < n) {
                            v.x += bf2f(u2.x); v.y += bf2f(u2.y);
                            v.z += bf2f(u2.z); v.w += bf2f(u2.w);
                        }
                        if (k + 3 < n) {
                            v.x += bf2f(u3.x); v.y += bf2f(u3.y);
                            v.z += bf2f(u3.z); v.w += bf2f(u3.w);
                        }
                    }
                    v.x = fmaxf(v.x, 0.f); v.y = fmaxf(v.y, 0.f);
                    v.z = fmaxf(v.z, 0.f); v.w = fmaxf(v.w, 0.f);
                }
            }
            ushort4 av;
            av.x = f2bf(v.x); av.y = f2bf(v.y); av.z = f2bf(v.z); av.w = f2bf(v.w);
            *(ushort4*)&At[rw][j * 4] = av;
        }
    }
    __syncthreads();

    // ---- MFMA main: wave w owns nodes w*32..w*32+31 (2 node-tiles) x 8 col-tiles
    int w  = t >> 6;
    int l  = t & 63;
    int ln = l & 15;
    int lk = l >> 4;
    f32x4 acc[2][8];
#pragma unroll
    for (int nt = 0; nt < 2; ++nt)
#pragma unroll
        for (int ct = 0; ct < 8; ++ct)
            acc[nt][ct] = (f32x4){0.f, 0.f, 0.f, 0.f};

    bf16x8 af[2][2];
#pragma unroll
    for (int nt = 0; nt < 2; ++nt)
#pragma unroll
        for (int ks = 0; ks < 2; ++ks)
            af[nt][ks] = *(const bf16x8*)&At[w * 32 + nt * 16 + ln][ks * 32 + lk * 8];

#pragma unroll
    for (int ct = 0; ct < 8; ++ct) {
        bf16x8 bf0 = *(const bf16x8*)&Bt[ct * 16 + ln][lk * 8];
        bf16x8 bf1 = *(const bf16x8*)&Bt[ct * 16 + ln][32 + lk * 8];
#pragma unroll
        for (int nt = 0; nt < 2; ++nt) {
            acc[nt][ct] = __builtin_amdgcn_mfma_f32_16x16x32_bf16(bf0, af[nt][0], acc[nt][ct], 0, 0, 0);
            acc[nt][ct] = __builtin_amdgcn_mfma_f32_16x16x32_bf16(bf1, af[nt][1], acc[nt][ct], 0, 0, 0);
        }
    }

    // ---- epilogue: lane holds node=ln, 4 consecutive cols per reg-quad; bf16 both halves
#pragma unroll
    for (int ct = 0; ct < 8; ++ct) {
        int c0 = ct * 16 + lk * 4;
#pragma unroll
        for (int nt = 0; nt < 2; ++nt) {
            int node = n0 + w * 32 + nt * 16 + ln;
            if (node >= nN) continue;
            f32x4 v = acc[nt][ct];
            if (ct < 4) {
                uint2 u;
                u.x = pk2(v[0], v[1]);
                u.y = pk2(v[2], v[3]);
                *(uint2*)(Y16 + (size_t)node * 64 + c0) = u;
            } else {
                const float4 bv = *(const float4*)(bias + (c0 - 64));
                uint2 u;
                u.x = pk2(v[0] + bv.x, v[1] + bv.y);
                u.y = pk2(v[2] + bv.z, v[3] + bv.w);
                *(uint2*)(P16 + (size_t)node * 64 + (c0 - 64)) = u;
            }
        }
    }
}

// ---------------------------------------------------------------------------
// fused0: blocks [0, GEMM_BLOCKS) run layer-0 gemm (A = x); remaining blocks
// run the vectorized bucket fill (4 edges/thread).
// ---------------------------------------------------------------------------
__global__ __launch_bounds__(256) void fused0_kernel(
    const float* __restrict__ x,
    const int* __restrict__ src, const int* __restrict__ dst,
    const int* __restrict__ et, int* __restrict__ cnt, int* __restrict__ bucket,
    const float* __restrict__ Wm, const float* __restrict__ Rm,
    const float* __restrict__ bias,
    unsigned short* __restrict__ Y16, unsigned short* __restrict__ P16, int nN)
{
    if (blockIdx.x < GEMM_BLOCKS) {
        gemm_body(blockIdx.x, x, nullptr, nullptr, nullptr, nullptr, -1,
                  Wm, Rm, bias, Y16, P16, nN);
    } else {
        int e0 = ((blockIdx.x - GEMM_BLOCKS) * 256 + threadIdx.x) * 4;
        fill_body4(src, dst, et, cnt, bucket, e0);
    }
}

// ---------------------------------------------------------------------------
// gemm_node: layers 1,2 (gather fused in A-stage)
// ---------------------------------------------------------------------------
__global__ __launch_bounds__(256) void gemm_node_kernel(
    const unsigned short* __restrict__ Pp, const unsigned short* __restrict__ Yp,
    const int* __restrict__ cnt, const int* __restrict__ bucket, int rel,
    const float* __restrict__ Wm, const float* __restrict__ Rm,
    const float* __restrict__ bias,
    unsigned short* __restrict__ Y16, unsigned short* __restrict__ P16, int nN)
{
    gemm_body(blockIdx.x, nullptr, Pp, Yp, cnt, bucket, rel,
              Wm, Rm, bias, Y16, P16, nN);
}

// ---------------------------------------------------------------------------
// final (MFMA): 16 nodes/wave; row = relu(bf16 P2[n] + gather(rel2)); logits
// via swapped mfma; log_softmax with 2 shfl_xor; one float4 store per lane.
// R16: edge loop batched 2-deep (8 independent row-chunk loads in flight).
// ---------------------------------------------------------------------------
__global__ __launch_bounds__(256) void final_kernel(
    const unsigned short* __restrict__ P2, const unsigned short* __restrict__ Y2,
    const int* __restrict__ cnt, const int* __restrict__ bucket, int rel,
    const float* __restrict__ Wl, const float* __restrict__ bl,
    float* __restrict__ out, int nN)
{
    int t = threadIdx.x;
    int w = t >> 6, l = t & 63;
    int ln = l & 15, lk = l >> 4;
    int node = blockIdx.x * 64 + w * 16 + ln;

    bf16x8 wf[2];
#pragma unroll
    for (int ks = 0; ks < 2; ++ks) {
        union { bf16x8 v; unsigned short u[8]; } tmp;
#pragma unroll
        for (int i = 0; i < 8; ++i)
            tmp.u[i] = f2bf(Wl[(ks * 32 + lk * 8 + i) * 16 + ln]);
        wf[ks] = tmp.v;
    }

    float v[16];
#pragma unroll
    for (int i = 0; i < 16; ++i) v[i] = 0.f;
    if (node < nN) {
#pragma unroll
        for (int ks = 0; ks < 2; ++ks) {
            uint4 pu = *(const uint4*)(P2 + (size_t)node * 64 + ks * 32 + lk * 8);
            v[ks * 8 + 0] = lo16(pu.x); v[ks * 8 + 1] = hi16(pu.x);
            v[ks * 8 + 2] = lo16(pu.y); v[ks * 8 + 3] = hi16(pu.y);
            v[ks * 8 + 4] = lo16(pu.z); v[ks * 8 + 5] = hi16(pu.z);
            v[ks * 8 + 6] = lo16(pu.w); v[ks * 8 + 7] = hi16(pu.w);
        }
        int base = rel * N_NODES + node;
        int n = cnt[base]; if (n > BCAP) n = BCAP;
        const int* brow = bucket + (size_t)base * BCAP;
        for (int k = 0; k < n; k += 2) {
            int dn0 = brow[k];
            int dn1 = (k + 1 < n) ? brow[k + 1] : dn0;
            uint4 a0 = *(const uint4*)(Y2 + (size_t)dn0 * 64 + lk * 8);
            uint4 a1 = *(const uint4*)(Y2 + (size_t)dn0 * 64 + 32 + lk * 8);
            uint4 b0 = *(const uint4*)(Y2 + (size_t)dn1 * 64 + lk * 8);
            uint4 b1 = *(const uint4*)(Y2 + (size_t)dn1 * 64 + 32 + lk * 8);
            v[0] += lo16(a0.x); v[1] += hi16(a0.x);
            v[2] += lo16(a0.y); v[3] += hi16(a0.y);
            v[4] += lo16(a0.z); v[5] += hi16(a0.z);
            v[6] += lo16(a0.w); v[7] += hi16(a0.w);
            v[8]  += lo16(a1.x); v[9]  += hi16(a1.x);
            v[10] += lo16(a1.y); v[11] += hi16(a1.y);
            v[12] += lo16(a1.z); v[13] += hi16(a1.z);
            v[14] += lo16(a1.w); v[15] += hi16(a1.w);
            if (k + 1 < n) {
                v[0] += lo16(b0.x); v[1] += hi16(b0.x);
                v[2] += lo16(b0.y); v[3] += hi16(b0.y);
                v[4] += lo16(b0.z); v[5] += hi16(b0.z);
                v[6] += lo16(b0.w); v[7] += hi16(b0.w);
                v[8]  += lo16(b1.x); v[9]  += hi16(b1.x);
                v[10] += lo16(b1.y); v[11] += hi16(b1.y);
                v[12] += lo16(b1.z); v[13] += hi16(b1.z);
                v[14] += lo16(b1.w); v[15] += hi16(b1.w);
            }
        }
#pragma unroll
        for (int i = 0; i < 16; ++i) v[i] = fmaxf(v[i], 0.f);
    }
    union { bf16x8 bv; unsigned short u[8]; } af[2];
#pragma unroll
    for (int ks = 0; ks < 2; ++ks)
#pragma unroll
        for (int i = 0; i < 8; ++i) af[ks].u[i] = f2bf(v[ks * 8 + i]);

    f32x4 acc = (f32x4){0.f, 0.f, 0.f, 0.f};
    acc = __builtin_amdgcn_mfma_f32_16x16x32_bf16(wf[0], af[0].bv, acc, 0, 0, 0);
    acc = __builtin_amdgcn_mfma_f32_16x16x32_bf16(wf[1], af[1].bv, acc, 0, 0, 0);

    if (node < nN) {
        float4 blv = *(const float4*)(bl + lk * 4);
        float p0 = acc[0] + blv.x, p1 = acc[1] + blv.y;
        float p2 = acc[2] + blv.z, p3 = acc[3] + blv.w;
        float mx = fmaxf(fmaxf(p0, p1), fmaxf(p2, p3));
        mx = fmaxf(mx, __shfl_xor(mx, 16));
        mx = fmaxf(mx, __shfl_xor(mx, 32));
        float s = __expf(p0 - mx) + __expf(p1 - mx) + __expf(p2 - mx) + __expf(p3 - mx);
        s += __shfl_xor(s, 16);
        s += __shfl_xor(s, 32);
        float ls = logf(s) + mx;
        float4 r = make_float4(p0 - ls, p1 - ls, p2 - ls, p3 - ls);
        *(float4*)(out + (size_t)node * 16 + lk * 4) = r;
    }
}

extern "C" void kernel_launch(void* const* d_in, const int* in_sizes, int n_in,
                              void* d_out, int out_size, void* d_ws, size_t ws_size,
                              hipStream_t stream) {
    const float* x     = (const float*)d_in[0];
    const int*   ei    = (const int*)  d_in[1];   // [2, E]
    const int*   et    = (const int*)  d_in[2];   // [E]
    const float* W1    = (const float*)d_in[3];   // [5,64,64]
    const float* root1 = (const float*)d_in[4];   // [64,64]
    const float* b1    = (const float*)d_in[5];   // [64]
    const float* W2    = (const float*)d_in[6];   // [5,64,64]
    const float* root2 = (const float*)d_in[7];   // [64,64]
    const float* b2    = (const float*)d_in[8];   // [64]
    const float* Wl    = (const float*)d_in[9];   // [64,16]
    const float* bl    = (const float*)d_in[10];  // [16]
    float* out = (float*)d_out;

    const int N = N_NODES, E = N_EDGES;
    const size_t hBytes   = (size_t)N * D * sizeof(unsigned short);           // 12.8 MB
    const size_t cntBytes = ((size_t)N3 * sizeof(int) + 255) & ~(size_t)255;  // 1.2 MB
    const size_t bktBytes = ((size_t)N3 * BCAP * sizeof(int) + 255) & ~(size_t)255; // 19.2 MB

    char* ws = (char*)d_ws;
    unsigned short* Ya = (unsigned short*)ws;                 ws += hBytes;
    unsigned short* Yb = (unsigned short*)ws;                 ws += hBytes;
    unsigned short* Pa = (unsigned short*)ws;                 ws += hBytes;
    unsigned short* Pb = (unsigned short*)ws;                 ws += hBytes;
    int* cnt    = (int*)ws;                                   ws += cntBytes;
    int* bucket = (int*)ws;                                   ws += bktBytes;

    const int* src = ei;       // edge_index[0]
    const int* dst = ei + E;   // edge_index[1]

    const int finalBlocks = (N + 63) / 64;

    // ---- counters must be zero before fill
    hipMemsetAsync(cnt, 0, (size_t)N3 * sizeof(int), stream);

    // ---- fused: layer-0 gemm (A = x) + vectorized bucket fill
    fused0_kernel<<<GEMM_BLOCKS + FILL_BLOCKS, 256, 0, stream>>>(
        x, src, dst, et, cnt, bucket, W1 + 0 * D * D, root1, b1, Ya, Pa, N);

    // ---- layer 1: A = relu(Pa + gather(rel0, Ya)); W2[1]/root2/b2 -> (Yb, Pb)
    gemm_node_kernel<<<GEMM_BLOCKS, 256, 0, stream>>>(
        Pa, Ya, cnt, bucket, 0, W2 + 1 * D * D, root2, b2, Yb, Pb, N);

    // ---- layer 2: A = relu(Pb + gather(rel1, Yb)); W2[2]/root2/b2 -> (Ya, Pa)
    gemm_node_kernel<<<GEMM_BLOCKS, 256, 0, stream>>>(
        Pb, Yb, cnt, bucket, 1, W2 + 2 * D * D, root2, b2, Ya, Pa, N);

    // ---- final: relu(Pa + gather(rel2, Ya)) @ Wl + bl -> log_softmax
    final_kernel<<<finalBlocks, 256, 0, stream>>>(
        Pa, Ya, cnt, bucket, 2, Wl, bl, out, N);
}

// Round 17
// 108.489 us; speedup vs baseline: 1.2712x; 1.0361x over previous
//
#include <hip/hip_runtime.h>
#include <hip/hip_bf16.h>
#include <math.h>

#define N_NODES 100000
#define N_EDGES 1000000
#define D 64
#define N3 300000          // 3 relations x N_NODES buckets
#define BCAP 16            // bucket row = exactly one 64B line
#define BM 128             // rows per gemm block
#define AST 72             // At row stride (ushorts)
#define BST 72             // Bt col stride (ushorts)
#define GEMM_BLOCKS ((N_NODES + BM - 1) / BM)     // 782
#define FILL_BLOCKS ((N_EDGES + 1023) / 1024)     // 977 (4 edges/thread)

typedef __attribute__((ext_vector_type(8))) short bf16x8;
typedef __attribute__((ext_vector_type(4))) float f32x4;

static __device__ __forceinline__ float bf2f(unsigned short u) {
    union { unsigned int i; float f; } c; c.i = ((unsigned int)u) << 16; return c.f;
}
static __device__ __forceinline__ float lo16(unsigned int u) { return bf2f((unsigned short)(u & 0xffffu)); }
static __device__ __forceinline__ float hi16(unsigned int u) { return bf2f((unsigned short)(u >> 16)); }
static __device__ __forceinline__ unsigned short f2bf(float f) {
    union { float f; unsigned int i; } c; c.f = f;
    unsigned int i = c.i;
    return (unsigned short)((i + 0x7FFFu + ((i >> 16) & 1u)) >> 16);  // RNE
}
static __device__ __forceinline__ unsigned int pk2(float lo, float hi) {
    return (unsigned int)f2bf(lo) | ((unsigned int)f2bf(hi) << 16);
}

// ---------------------------------------------------------------------------
// fill body, 4 edges per thread (int4 loads): 4 independent atomic+store
// chains in flight per thread (R15: fused0 58.9 -> 43.4us).
// ---------------------------------------------------------------------------
static __device__ __forceinline__ void fill_body4(
    const int* __restrict__ src, const int* __restrict__ dst,
    const int* __restrict__ et, int* __restrict__ cnt, int* __restrict__ bucket,
    int e0)
{
    if (e0 >= N_EDGES) return;   // N_EDGES % 4 == 0
    int4 t4 = *(const int4*)(et + e0);
    int4 s4 = *(const int4*)(src + e0);
    int4 d4 = *(const int4*)(dst + e0);
    int t[4] = { t4.x, t4.y, t4.z, t4.w };
    int s[4] = { s4.x, s4.y, s4.z, s4.w };
    int d[4] = { d4.x, d4.y, d4.z, d4.w };
#pragma unroll
    for (int i = 0; i < 4; ++i) {
        if (t[i] < 3) {
            int base = t[i] * N_NODES + s[i];
            int pos = atomicAdd(&cnt[base], 1);
            if (pos < BCAP) bucket[(size_t)base * BCAP + pos] = d[i];
        }
    }
}

// ---------------------------------------------------------------------------
// gemm body (MFMA, swapped operands): tile [BM x 128] = A[BMx64] @ [W|root].
//   A[n] = x[n]                                (relG < 0, f32 input)
//   A[n] = relu(bf16(Pp[n]) + sum Yp[bucket])  (relG >= 0, gather fused)
// R17: A-stage CROSS-PASS PREFETCH — all 8 passes' cnt/bucket-row/P-row loads
// are independent; hoisting them into one block turns 8 serial 3-link chains
// (cnt -> brow -> Y, ~800cy each) into 1 latency + 8 in-flight Y batches.
// Bucket rows load unconditionally (addresses always in-range; entries >= n
// are never shuffled from — trip count is group-uniform).
// ---------------------------------------------------------------------------
static __device__ __forceinline__ void gemm_body(
    int bid,
    const float* __restrict__ Hin, const unsigned short* __restrict__ Pp,
    const unsigned short* __restrict__ Yp,
    const int* __restrict__ cnt, const int* __restrict__ bucket, int relG,
    const float* __restrict__ Wm, const float* __restrict__ Rm,
    const float* __restrict__ bias,
    unsigned short* __restrict__ Y16, unsigned short* __restrict__ P16, int nN)
{
    __shared__ unsigned short At[BM][AST];   // A rows, bf16 [row][k]
    __shared__ unsigned short Bt[128][BST];  // B cols, bf16 [col][k]
    int t = threadIdx.x;
    int n0 = bid * BM;

    // ---- stage B transposed: Bt[col][k] = bf16(B[k][col])
#pragma unroll
    for (int it = 0; it < 8; ++it) {
        int idx = t + it * 256;        // 0..2047
        int col = idx & 127;
        int k0  = (idx >> 7) * 4;
        const float* srcB = (col < 64) ? (Wm + col) : (Rm + col - 64);
        ushort4 wv;
        wv.x = f2bf(srcB[(k0 + 0) * 64]);
        wv.y = f2bf(srcB[(k0 + 1) * 64]);
        wv.z = f2bf(srcB[(k0 + 2) * 64]);
        wv.w = f2bf(srcB[(k0 + 3) * 64]);
        *(ushort4*)&Bt[col][k0] = wv;
    }

    // ---- stage A (fused gather with cross-pass prefetch), bf16 rows
    {
        int gidx = t >> 4, j = t & 15, lane = t & 63, grp = lane & 48;
        if (relG < 0) {
#pragma unroll
            for (int pass = 0; pass < 8; ++pass) {
                int rw = gidx + pass * 16;
                int node = n0 + rw;
                float4 v = make_float4(0.f, 0.f, 0.f, 0.f);
                if (node < nN) v = *(const float4*)(Hin + (size_t)node * 64 + j * 4);
                ushort4 av;
                av.x = f2bf(v.x); av.y = f2bf(v.y); av.z = f2bf(v.z); av.w = f2bf(v.w);
                *(ushort4*)&At[rw][j * 4] = av;
            }
        } else {
            // phase 1: issue all independent head loads (8x cnt, 8x brow, 8x P)
            int nn[8]; int bk[8]; ushort4 pv[8];
#pragma unroll
            for (int p = 0; p < 8; ++p) {
                int node = n0 + gidx + p * 16;
                int nodeC = (node < nN) ? node : 0;       // clamp: safe addr, result unused
                int base = relG * N_NODES + nodeC;
                nn[p] = cnt[base];
                bk[p] = bucket[(size_t)base * BCAP + j];  // unconditional
                pv[p] = *(const ushort4*)(Pp + (size_t)nodeC * 64 + j * 4);
            }
            // phase 2: per pass, gather Y rows (4-deep batched) + relu + LDS
#pragma unroll
            for (int p = 0; p < 8; ++p) {
                int rw = gidx + p * 16;
                int node = n0 + rw;
                float4 v = make_float4(0.f, 0.f, 0.f, 0.f);
                if (node < nN) {
                    v = make_float4(bf2f(pv[p].x), bf2f(pv[p].y),
                                    bf2f(pv[p].z), bf2f(pv[p].w));
                    int n = nn[p]; if (n > BCAP) n = BCAP;
                    for (int k = 0; k < n; k += 4) {
                        int i1 = (k + 1 < n) ? k + 1 : k;
                        int i2 = (k + 2 < n) ? k + 2 : k;
                        int i3 = (k + 3 < n) ? k + 3 : k;
                        int dn0 = __shfl(bk[p], grp | k);
                        int dn1 = __shfl(bk[p], grp | i1);
                        int dn2 = __shfl(bk[p], grp | i2);
                        int dn3 = __shfl(bk[p], grp | i3);
                        ushort4 u0 = *(const ushort4*)(Yp + (size_t)dn0 * 64 + j * 4);
                        ushort4 u1 = *(const ushort4*)(Yp + (size_t)dn1 * 64 + j * 4);
                        ushort4 u2 = *(const ushort4*)(Yp + (size_t)dn2 * 64 + j * 4);
                        ushort4 u3 = *(const ushort4*)(Yp + (size_t)dn3 * 64 + j * 4);
                        v.x += bf2f(u0.x); v.y += bf2f(u0.y);
                        v.z += bf2f(u0.z); v.w += bf2f(u0.w);
                        if (k + 1 < n) {
                            v.x += bf2f(u1.x); v.y += bf2f(u1.y);
                            v.z += bf2f(u1.z); v.w += bf2f(u1.w);
                        }
                        if (k + 2 < n) {
                            v.x += bf2f(u2.x); v.y += bf2f(u2.y);
                            v.z += bf2f(u2.z); v.w += bf2f(u2.w);
                        }
                        if (k + 3 < n) {
                            v.x += bf2f(u3.x); v.y += bf2f(u3.y);
                            v.z += bf2f(u3.z); v.w += bf2f(u3.w);
                        }
                    }
                    v.x = fmaxf(v.x, 0.f); v.y = fmaxf(v.y, 0.f);
                    v.z = fmaxf(v.z, 0.f); v.w = fmaxf(v.w, 0.f);
                }
                ushort4 av;
                av.x = f2bf(v.x); av.y = f2bf(v.y); av.z = f2bf(v.z); av.w = f2bf(v.w);
                *(ushort4*)&At[rw][j * 4] = av;
            }
        }
    }
    __syncthreads();

    // ---- MFMA main: wave w owns nodes w*32..w*32+31 (2 node-tiles) x 8 col-tiles
    int w  = t >> 6;
    int l  = t & 63;
    int ln = l & 15;
    int lk = l >> 4;
    f32x4 acc[2][8];
#pragma unroll
    for (int nt = 0; nt < 2; ++nt)
#pragma unroll
        for (int ct = 0; ct < 8; ++ct)
            acc[nt][ct] = (f32x4){0.f, 0.f, 0.f, 0.f};

    bf16x8 af[2][2];
#pragma unroll
    for (int nt = 0; nt < 2; ++nt)
#pragma unroll
        for (int ks = 0; ks < 2; ++ks)
            af[nt][ks] = *(const bf16x8*)&At[w * 32 + nt * 16 + ln][ks * 32 + lk * 8];

#pragma unroll
    for (int ct = 0; ct < 8; ++ct) {
        bf16x8 bf0 = *(const bf16x8*)&Bt[ct * 16 + ln][lk * 8];
        bf16x8 bf1 = *(const bf16x8*)&Bt[ct * 16 + ln][32 + lk * 8];
#pragma unroll
        for (int nt = 0; nt < 2; ++nt) {
            acc[nt][ct] = __builtin_amdgcn_mfma_f32_16x16x32_bf16(bf0, af[nt][0], acc[nt][ct], 0, 0, 0);
            acc[nt][ct] = __builtin_amdgcn_mfma_f32_16x16x32_bf16(bf1, af[nt][1], acc[nt][ct], 0, 0, 0);
        }
    }

    // ---- epilogue: lane holds node=ln, 4 consecutive cols per reg-quad; bf16 both halves
#pragma unroll
    for (int ct = 0; ct < 8; ++ct) {
        int c0 = ct * 16 + lk * 4;
#pragma unroll
        for (int nt = 0; nt < 2; ++nt) {
            int node = n0 + w * 32 + nt * 16 + ln;
            if (node >= nN) continue;
            f32x4 v = acc[nt][ct];
            if (ct < 4) {
                uint2 u;
                u.x = pk2(v[0], v[1]);
                u.y = pk2(v[2], v[3]);
                *(uint2*)(Y16 + (size_t)node * 64 + c0) = u;
            } else {
                const float4 bv = *(const float4*)(bias + (c0 - 64));
                uint2 u;
                u.x = pk2(v[0] + bv.x, v[1] + bv.y);
                u.y = pk2(v[2] + bv.z, v[3] + bv.w);
                *(uint2*)(P16 + (size_t)node * 64 + (c0 - 64)) = u;
            }
        }
    }
}

// ---------------------------------------------------------------------------
// fused0: blocks [0, GEMM_BLOCKS) run layer-0 gemm (A = x); remaining blocks
// run the vectorized bucket fill (4 edges/thread).
// ---------------------------------------------------------------------------
__global__ __launch_bounds__(256) void fused0_kernel(
    const float* __restrict__ x,
    const int* __restrict__ src, const int* __restrict__ dst,
    const int* __restrict__ et, int* __restrict__ cnt, int* __restrict__ bucket,
    const float* __restrict__ Wm, const float* __restrict__ Rm,
    const float* __restrict__ bias,
    unsigned short* __restrict__ Y16, unsigned short* __restrict__ P16, int nN)
{
    if (blockIdx.x < GEMM_BLOCKS) {
        gemm_body(blockIdx.x, x, nullptr, nullptr, nullptr, nullptr, -1,
                  Wm, Rm, bias, Y16, P16, nN);
    } else {
        int e0 = ((blockIdx.x - GEMM_BLOCKS) * 256 + threadIdx.x) * 4;
        fill_body4(src, dst, et, cnt, bucket, e0);
    }
}

// ---------------------------------------------------------------------------
// gemm_node: layers 1,2 (gather fused in A-stage)
// ---------------------------------------------------------------------------
__global__ __launch_bounds__(256) void gemm_node_kernel(
    const unsigned short* __restrict__ Pp, const unsigned short* __restrict__ Yp,
    const int* __restrict__ cnt, const int* __restrict__ bucket, int rel,
    const float* __restrict__ Wm, const float* __restrict__ Rm,
    const float* __restrict__ bias,
    unsigned short* __restrict__ Y16, unsigned short* __restrict__ P16, int nN)
{
    gemm_body(blockIdx.x, nullptr, Pp, Yp, cnt, bucket, rel,
              Wm, Rm, bias, Y16, P16, nN);
}

// ---------------------------------------------------------------------------
// final (MFMA): 16 nodes/wave; row = relu(bf16 P2[n] + gather(rel2)); logits
// via swapped mfma; log_softmax with 2 shfl_xor; one float4 store per lane.
// Edge loop batched 2-deep (8 independent row-chunk loads in flight).
// ---------------------------------------------------------------------------
__global__ __launch_bounds__(256) void final_kernel(
    const unsigned short* __restrict__ P2, const unsigned short* __restrict__ Y2,
    const int* __restrict__ cnt, const int* __restrict__ bucket, int rel,
    const float* __restrict__ Wl, const float* __restrict__ bl,
    float* __restrict__ out, int nN)
{
    int t = threadIdx.x;
    int w = t >> 6, l = t & 63;
    int ln = l & 15, lk = l >> 4;
    int node = blockIdx.x * 64 + w * 16 + ln;

    bf16x8 wf[2];
#pragma unroll
    for (int ks = 0; ks < 2; ++ks) {
        union { bf16x8 v; unsigned short u[8]; } tmp;
#pragma unroll
        for (int i = 0; i < 8; ++i)
            tmp.u[i] = f2bf(Wl[(ks * 32 + lk * 8 + i) * 16 + ln]);
        wf[ks] = tmp.v;
    }

    float v[16];
#pragma unroll
    for (int i = 0; i < 16; ++i) v[i] = 0.f;
    if (node < nN) {
#pragma unroll
        for (int ks = 0; ks < 2; ++ks) {
            uint4 pu = *(const uint4*)(P2 + (size_t)node * 64 + ks * 32 + lk * 8);
            v[ks * 8 + 0] = lo16(pu.x); v[ks * 8 + 1] = hi16(pu.x);
            v[ks * 8 + 2] = lo16(pu.y); v[ks * 8 + 3] = hi16(pu.y);
            v[ks * 8 + 4] = lo16(pu.z); v[ks * 8 + 5] = hi16(pu.z);
            v[ks * 8 + 6] = lo16(pu.w); v[ks * 8 + 7] = hi16(pu.w);
        }
        int base = rel * N_NODES + node;
        int n = cnt[base]; if (n > BCAP) n = BCAP;
        const int* brow = bucket + (size_t)base * BCAP;
        for (int k = 0; k < n; k += 2) {
            int dn0 = brow[k];
            int dn1 = (k + 1 < n) ? brow[k + 1] : dn0;
            uint4 a0 = *(const uint4*)(Y2 + (size_t)dn0 * 64 + lk * 8);
            uint4 a1 = *(const uint4*)(Y2 + (size_t)dn0 * 64 + 32 + lk * 8);
            uint4 b0 = *(const uint4*)(Y2 + (size_t)dn1 * 64 + lk * 8);
            uint4 b1 = *(const uint4*)(Y2 + (size_t)dn1 * 64 + 32 + lk * 8);
            v[0] += lo16(a0.x); v[1] += hi16(a0.x);
            v[2] += lo16(a0.y); v[3] += hi16(a0.y);
            v[4] += lo16(a0.z); v[5] += hi16(a0.z);
            v[6] += lo16(a0.w); v[7] += hi16(a0.w);
            v[8]  += lo16(a1.x); v[9]  += hi16(a1.x);
            v[10] += lo16(a1.y); v[11] += hi16(a1.y);
            v[12] += lo16(a1.z); v[13] += hi16(a1.z);
            v[14] += lo16(a1.w); v[15] += hi16(a1.w);
            if (k + 1 < n) {
                v[0] += lo16(b0.x); v[1] += hi16(b0.x);
                v[2] += lo16(b0.y); v[3] += hi16(b0.y);
                v[4] += lo16(b0.z); v[5] += hi16(b0.z);
                v[6] += lo16(b0.w); v[7] += hi16(b0.w);
                v[8]  += lo16(b1.x); v[9]  += hi16(b1.x);
                v[10] += lo16(b1.y); v[11] += hi16(b1.y);
                v[12] += lo16(b1.z); v[13] += hi16(b1.z);
                v[14] += lo16(b1.w); v[15] += hi16(b1.w);
            }
        }
#pragma unroll
        for (int i = 0; i < 16; ++i) v[i] = fmaxf(v[i], 0.f);
    }
    union { bf16x8 bv; unsigned short u[8]; } af[2];
#pragma unroll
    for (int ks = 0; ks < 2; ++ks)
#pragma unroll
        for (int i = 0; i < 8; ++i) af[ks].u[i] = f2bf(v[ks * 8 + i]);

    f32x4 acc = (f32x4){0.f, 0.f, 0.f, 0.f};
    acc = __builtin_amdgcn_mfma_f32_16x16x32_bf16(wf[0], af[0].bv, acc, 0, 0, 0);
    acc = __builtin_amdgcn_mfma_f32_16x16x32_bf16(wf[1], af[1].bv, acc, 0, 0, 0);

    if (node < nN) {
        float4 blv = *(const float4*)(bl + lk * 4);
        float p0 = acc[0] + blv.x, p1 = acc[1] + blv.y;
        float p2 = acc[2] + blv.z, p3 = acc[3] + blv.w;
        float mx = fmaxf(fmaxf(p0, p1), fmaxf(p2, p3));
        mx = fmaxf(mx, __shfl_xor(mx, 16));
        mx = fmaxf(mx, __shfl_xor(mx, 32));
        float s = __expf(p0 - mx) + __expf(p1 - mx) + __expf(p2 - mx) + __expf(p3 - mx);
        s += __shfl_xor(s, 16);
        s += __shfl_xor(s, 32);
        float ls = logf(s) + mx;
        float4 r = make_float4(p0 - ls, p1 - ls, p2 - ls, p3 - ls);
        *(float4*)(out + (size_t)node * 16 + lk * 4) = r;
    }
}

extern "C" void kernel_launch(void* const* d_in, const int* in_sizes, int n_in,
                              void* d_out, int out_size, void* d_ws, size_t ws_size,
                              hipStream_t stream) {
    const float* x     = (const float*)d_in[0];
    const int*   ei    = (const int*)  d_in[1];   // [2, E]
    const int*   et    = (const int*)  d_in[2];   // [E]
    const float* W1    = (const float*)d_in[3];   // [5,64,64]
    const float* root1 = (const float*)d_in[4];   // [64,64]
    const float* b1    = (const float*)d_in[5];   // [64]
    const float* W2    = (const float*)d_in[6];   // [5,64,64]
    const float* root2 = (const float*)d_in[7];   // [64,64]
    const float* b2    = (const float*)d_in[8];   // [64]
    const float* Wl    = (const float*)d_in[9];   // [64,16]
    const float* bl    = (const float*)d_in[10];  // [16]
    float* out = (float*)d_out;

    const int N = N_NODES, E = N_EDGES;
    const size_t hBytes   = (size_t)N * D * sizeof(unsigned short);           // 12.8 MB
    const size_t cntBytes = ((size_t)N3 * sizeof(int) + 255) & ~(size_t)255;  // 1.2 MB
    const size_t bktBytes = ((size_t)N3 * BCAP * sizeof(int) + 255) & ~(size_t)255; // 19.2 MB

    char* ws = (char*)d_ws;
    unsigned short* Ya = (unsigned short*)ws;                 ws += hBytes;
    unsigned short* Yb = (unsigned short*)ws;                 ws += hBytes;
    unsigned short* Pa = (unsigned short*)ws;                 ws += hBytes;
    unsigned short* Pb = (unsigned short*)ws;                 ws += hBytes;
    int* cnt    = (int*)ws;                                   ws += cntBytes;
    int* bucket = (int*)ws;                                   ws += bktBytes;

    const int* src = ei;       // edge_index[0]
    const int* dst = ei + E;   // edge_index[1]

    const int finalBlocks = (N + 63) / 64;

    // ---- counters must be zero before fill
    hipMemsetAsync(cnt, 0, (size_t)N3 * sizeof(int), stream);

    // ---- fused: layer-0 gemm (A = x) + vectorized bucket fill
    fused0_kernel<<<GEMM_BLOCKS + FILL_BLOCKS, 256, 0, stream>>>(
        x, src, dst, et, cnt, bucket, W1 + 0 * D * D, root1, b1, Ya, Pa, N);

    // ---- layer 1: A = relu(Pa + gather(rel0, Ya)); W2[1]/root2/b2 -> (Yb, Pb)
    gemm_node_kernel<<<GEMM_BLOCKS, 256, 0, stream>>>(
        Pa, Ya, cnt, bucket, 0, W2 + 1 * D * D, root2, b2, Yb, Pb, N);

    // ---- layer 2: A = relu(Pb + gather(rel1, Yb)); W2[2]/root2/b2 -> (Ya, Pa)
    gemm_node_kernel<<<GEMM_BLOCKS, 256, 0, stream>>>(
        Pb, Yb, cnt, bucket, 1, W2 + 2 * D * D, root2, b2, Ya, Pa, N);

    // ---- final: relu(Pa + gather(rel2, Ya)) @ Wl + bl -> log_softmax
    final_kernel<<<finalBlocks, 256, 0, stream>>>(
        Pa, Ya, cnt, bucket, 2, Wl, bl, out, N);
}

// Round 18
// 95.285 us; speedup vs baseline: 1.4473x; 1.1386x over previous
//
#include <hip/hip_runtime.h>
#include <hip/hip_bf16.h>
#include <math.h>

#define N_NODES 100000
#define N_EDGES 1000000
#define D 64
#define N3 300000          // 3 relations x N_NODES buckets
#define BCAP 16            // bucket row = exactly one 64B line
#define BM 128             // rows per gemm block
#define AST 72             // At row stride (ushorts)
#define BST 72             // Bt col stride (ushorts)
#define GEMM_BLOCKS ((N_NODES + BM - 1) / BM)     // 782
#define FILL_BLOCKS ((N_EDGES + 1023) / 1024)     // 977 (4 edges/thread)

typedef __attribute__((ext_vector_type(8))) short bf16x8;
typedef __attribute__((ext_vector_type(4))) float f32x4;

static __device__ __forceinline__ float bf2f(unsigned short u) {
    union { unsigned int i; float f; } c; c.i = ((unsigned int)u) << 16; return c.f;
}
static __device__ __forceinline__ float lo16(unsigned int u) { return bf2f((unsigned short)(u & 0xffffu)); }
static __device__ __forceinline__ float hi16(unsigned int u) { return bf2f((unsigned short)(u >> 16)); }
static __device__ __forceinline__ unsigned short f2bf(float f) {
    union { float f; unsigned int i; } c; c.f = f;
    unsigned int i = c.i;
    return (unsigned short)((i + 0x7FFFu + ((i >> 16) & 1u)) >> 16);  // RNE
}
static __device__ __forceinline__ unsigned int pk2(float lo, float hi) {
    return (unsigned int)f2bf(lo) | ((unsigned int)f2bf(hi) << 16);
}

// ---------------------------------------------------------------------------
// fill body, 4 edges per thread, ONE relation per pass. R11's "slice == full
// cost" was measured on the scalar 1-edge/thread fill (scan-latency-bound);
// with int4 + 4 independent chains (R15) the cost is scatter-transaction-
// bound and scales with matching-edge count (~14us per 200k-edge relation).
// Scatter slices pipeline across layer launches; bucket/cnt index ranges are
// disjoint per rel, and launch boundaries order producer->consumer.
// ---------------------------------------------------------------------------
static __device__ __forceinline__ void fill_body4(
    const int* __restrict__ src, const int* __restrict__ dst,
    const int* __restrict__ et, int* __restrict__ cnt, int* __restrict__ bucket,
    int e0, int rel)
{
    if (e0 >= N_EDGES) return;   // N_EDGES % 4 == 0
    int4 t4 = *(const int4*)(et + e0);
    int4 s4 = *(const int4*)(src + e0);
    int4 d4 = *(const int4*)(dst + e0);
    int t[4] = { t4.x, t4.y, t4.z, t4.w };
    int s[4] = { s4.x, s4.y, s4.z, s4.w };
    int d[4] = { d4.x, d4.y, d4.z, d4.w };
#pragma unroll
    for (int i = 0; i < 4; ++i) {
        if (t[i] == rel) {
            int base = rel * N_NODES + s[i];
            int pos = atomicAdd(&cnt[base], 1);
            if (pos < BCAP) bucket[(size_t)base * BCAP + pos] = d[i];
        }
    }
}

// ---------------------------------------------------------------------------
// gemm body (MFMA, swapped operands): tile [BM x 128] = A[BMx64] @ [W|root].
//   A[n] = x[n]                                (relG < 0, f32 input)
//   A[n] = relu(bf16(Pp[n]) + sum Yp[bucket])  (relG >= 0, gather fused)
// A-stage cross-pass prefetch (R17) + 4-deep Y-gather batching (R16).
// ---------------------------------------------------------------------------
static __device__ __forceinline__ void gemm_body(
    int bid,
    const float* __restrict__ Hin, const unsigned short* __restrict__ Pp,
    const unsigned short* __restrict__ Yp,
    const int* __restrict__ cnt, const int* __restrict__ bucket, int relG,
    const float* __restrict__ Wm, const float* __restrict__ Rm,
    const float* __restrict__ bias,
    unsigned short* __restrict__ Y16, unsigned short* __restrict__ P16, int nN)
{
    __shared__ unsigned short At[BM][AST];   // A rows, bf16 [row][k]
    __shared__ unsigned short Bt[128][BST];  // B cols, bf16 [col][k]
    int t = threadIdx.x;
    int n0 = bid * BM;

    // ---- stage B transposed: Bt[col][k] = bf16(B[k][col])
#pragma unroll
    for (int it = 0; it < 8; ++it) {
        int idx = t + it * 256;        // 0..2047
        int col = idx & 127;
        int k0  = (idx >> 7) * 4;
        const float* srcB = (col < 64) ? (Wm + col) : (Rm + col - 64);
        ushort4 wv;
        wv.x = f2bf(srcB[(k0 + 0) * 64]);
        wv.y = f2bf(srcB[(k0 + 1) * 64]);
        wv.z = f2bf(srcB[(k0 + 2) * 64]);
        wv.w = f2bf(srcB[(k0 + 3) * 64]);
        *(ushort4*)&Bt[col][k0] = wv;
    }

    // ---- stage A (fused gather with cross-pass prefetch), bf16 rows
    {
        int gidx = t >> 4, j = t & 15, lane = t & 63, grp = lane & 48;
        if (relG < 0) {
#pragma unroll
            for (int pass = 0; pass < 8; ++pass) {
                int rw = gidx + pass * 16;
                int node = n0 + rw;
                float4 v = make_float4(0.f, 0.f, 0.f, 0.f);
                if (node < nN) v = *(const float4*)(Hin + (size_t)node * 64 + j * 4);
                ushort4 av;
                av.x = f2bf(v.x); av.y = f2bf(v.y); av.z = f2bf(v.z); av.w = f2bf(v.w);
                *(ushort4*)&At[rw][j * 4] = av;
            }
        } else {
            // phase 1: issue all independent head loads (8x cnt, 8x brow, 8x P)
            int nn[8]; int bk[8]; ushort4 pv[8];
#pragma unroll
            for (int p = 0; p < 8; ++p) {
                int node = n0 + gidx + p * 16;
                int nodeC = (node < nN) ? node : 0;       // clamp: safe addr, result unused
                int base = relG * N_NODES + nodeC;
                nn[p] = cnt[base];
                bk[p] = bucket[(size_t)base * BCAP + j];  // unconditional
                pv[p] = *(const ushort4*)(Pp + (size_t)nodeC * 64 + j * 4);
            }
            // phase 2: per pass, gather Y rows (4-deep batched) + relu + LDS
#pragma unroll
            for (int p = 0; p < 8; ++p) {
                int rw = gidx + p * 16;
                int node = n0 + rw;
                float4 v = make_float4(0.f, 0.f, 0.f, 0.f);
                if (node < nN) {
                    v = make_float4(bf2f(pv[p].x), bf2f(pv[p].y),
                                    bf2f(pv[p].z), bf2f(pv[p].w));
                    int n = nn[p]; if (n > BCAP) n = BCAP;
                    for (int k = 0; k < n; k += 4) {
                        int i1 = (k + 1 < n) ? k + 1 : k;
                        int i2 = (k + 2 < n) ? k + 2 : k;
                        int i3 = (k + 3 < n) ? k + 3 : k;
                        int dn0 = __shfl(bk[p], grp | k);
                        int dn1 = __shfl(bk[p], grp | i1);
                        int dn2 = __shfl(bk[p], grp | i2);
                        int dn3 = __shfl(bk[p], grp | i3);
                        ushort4 u0 = *(const ushort4*)(Yp + (size_t)dn0 * 64 + j * 4);
                        ushort4 u1 = *(const ushort4*)(Yp + (size_t)dn1 * 64 + j * 4);
                        ushort4 u2 = *(const ushort4*)(Yp + (size_t)dn2 * 64 + j * 4);
                        ushort4 u3 = *(const ushort4*)(Yp + (size_t)dn3 * 64 + j * 4);
                        v.x += bf2f(u0.x); v.y += bf2f(u0.y);
                        v.z += bf2f(u0.z); v.w += bf2f(u0.w);
                        if (k + 1 < n) {
                            v.x += bf2f(u1.x); v.y += bf2f(u1.y);
                            v.z += bf2f(u1.z); v.w += bf2f(u1.w);
                        }
                        if (k + 2 < n) {
                            v.x += bf2f(u2.x); v.y += bf2f(u2.y);
                            v.z += bf2f(u2.z); v.w += bf2f(u2.w);
                        }
                        if (k + 3 < n) {
                            v.x += bf2f(u3.x); v.y += bf2f(u3.y);
                            v.z += bf2f(u3.z); v.w += bf2f(u3.w);
                        }
                    }
                    v.x = fmaxf(v.x, 0.f); v.y = fmaxf(v.y, 0.f);
                    v.z = fmaxf(v.z, 0.f); v.w = fmaxf(v.w, 0.f);
                }
                ushort4 av;
                av.x = f2bf(v.x); av.y = f2bf(v.y); av.z = f2bf(v.z); av.w = f2bf(v.w);
                *(ushort4*)&At[rw][j * 4] = av;
            }
        }
    }
    __syncthreads();

    // ---- MFMA main: wave w owns nodes w*32..w*32+31 (2 node-tiles) x 8 col-tiles
    int w  = t >> 6;
    int l  = t & 63;
    int ln = l & 15;
    int lk = l >> 4;
    f32x4 acc[2][8];
#pragma unroll
    for (int nt = 0; nt < 2; ++nt)
#pragma unroll
        for (int ct = 0; ct < 8; ++ct)
            acc[nt][ct] = (f32x4){0.f, 0.f, 0.f, 0.f};

    bf16x8 af[2][2];
#pragma unroll
    for (int nt = 0; nt < 2; ++nt)
#pragma unroll
        for (int ks = 0; ks < 2; ++ks)
            af[nt][ks] = *(const bf16x8*)&At[w * 32 + nt * 16 + ln][ks * 32 + lk * 8];

#pragma unroll
    for (int ct = 0; ct < 8; ++ct) {
        bf16x8 bf0 = *(const bf16x8*)&Bt[ct * 16 + ln][lk * 8];
        bf16x8 bf1 = *(const bf16x8*)&Bt[ct * 16 + ln][32 + lk * 8];
#pragma unroll
        for (int nt = 0; nt < 2; ++nt) {
            acc[nt][ct] = __builtin_amdgcn_mfma_f32_16x16x32_bf16(bf0, af[nt][0], acc[nt][ct], 0, 0, 0);
            acc[nt][ct] = __builtin_amdgcn_mfma_f32_16x16x32_bf16(bf1, af[nt][1], acc[nt][ct], 0, 0, 0);
        }
    }

    // ---- epilogue: lane holds node=ln, 4 consecutive cols per reg-quad; bf16 both halves
#pragma unroll
    for (int ct = 0; ct < 8; ++ct) {
        int c0 = ct * 16 + lk * 4;
#pragma unroll
        for (int nt = 0; nt < 2; ++nt) {
            int node = n0 + w * 32 + nt * 16 + ln;
            if (node >= nN) continue;
            f32x4 v = acc[nt][ct];
            if (ct < 4) {
                uint2 u;
                u.x = pk2(v[0], v[1]);
                u.y = pk2(v[2], v[3]);
                *(uint2*)(Y16 + (size_t)node * 64 + c0) = u;
            } else {
                const float4 bv = *(const float4*)(bias + (c0 - 64));
                uint2 u;
                u.x = pk2(v[0] + bv.x, v[1] + bv.y);
                u.y = pk2(v[2] + bv.z, v[3] + bv.w);
                *(uint2*)(P16 + (size_t)node * 64 + (c0 - 64)) = u;
            }
        }
    }
}

// ---------------------------------------------------------------------------
// fused0: blocks [0, GEMM_BLOCKS) run layer-0 gemm (A = x); remaining blocks
// scatter relation 0's edges (needed by gemm1).
// ---------------------------------------------------------------------------
__global__ __launch_bounds__(256) void fused0_kernel(
    const float* __restrict__ x,
    const int* __restrict__ src, const int* __restrict__ dst,
    const int* __restrict__ et, int* __restrict__ cnt, int* __restrict__ bucket,
    const float* __restrict__ Wm, const float* __restrict__ Rm,
    const float* __restrict__ bias,
    unsigned short* __restrict__ Y16, unsigned short* __restrict__ P16, int nN)
{
    if (blockIdx.x < GEMM_BLOCKS) {
        gemm_body(blockIdx.x, x, nullptr, nullptr, nullptr, nullptr, -1,
                  Wm, Rm, bias, Y16, P16, nN);
    } else {
        int e0 = ((blockIdx.x - GEMM_BLOCKS) * 256 + threadIdx.x) * 4;
        fill_body4(src, dst, et, cnt, bucket, e0, 0);
    }
}

// ---------------------------------------------------------------------------
// gemm_fill: layers 1,2 — gemm (gathering relG, filled in a previous launch)
// with relation relF's scatter fused behind it. Disjoint bucket ranges.
// ---------------------------------------------------------------------------
__global__ __launch_bounds__(256) void gemm_fill_kernel(
    const unsigned short* __restrict__ Pp, const unsigned short* __restrict__ Yp,
    const int* __restrict__ src, const int* __restrict__ dst,
    const int* __restrict__ et, int* __restrict__ cnt, int* __restrict__ bucket,
    int relG, int relF,
    const float* __restrict__ Wm, const float* __restrict__ Rm,
    const float* __restrict__ bias,
    unsigned short* __restrict__ Y16, unsigned short* __restrict__ P16, int nN)
{
    if (blockIdx.x < GEMM_BLOCKS) {
        gemm_body(blockIdx.x, nullptr, Pp, Yp, cnt, bucket, relG,
                  Wm, Rm, bias, Y16, P16, nN);
    } else {
        int e0 = ((blockIdx.x - GEMM_BLOCKS) * 256 + threadIdx.x) * 4;
        fill_body4(src, dst, et, cnt, bucket, e0, relF);
    }
}

// ---------------------------------------------------------------------------
// final (MFMA): 16 nodes/wave; row = relu(bf16 P2[n] + gather(rel2)); logits
// via swapped mfma; log_softmax with 2 shfl_xor; one float4 store per lane.
// Edge loop batched 2-deep (8 independent row-chunk loads in flight).
// ---------------------------------------------------------------------------
__global__ __launch_bounds__(256) void final_kernel(
    const unsigned short* __restrict__ P2, const unsigned short* __restrict__ Y2,
    const int* __restrict__ cnt, const int* __restrict__ bucket, int rel,
    const float* __restrict__ Wl, const float* __restrict__ bl,
    float* __restrict__ out, int nN)
{
    int t = threadIdx.x;
    int w = t >> 6, l = t & 63;
    int ln = l & 15, lk = l >> 4;
    int node = blockIdx.x * 64 + w * 16 + ln;

    bf16x8 wf[2];
#pragma unroll
    for (int ks = 0; ks < 2; ++ks) {
        union { bf16x8 v; unsigned short u[8]; } tmp;
#pragma unroll
        for (int i = 0; i < 8; ++i)
            tmp.u[i] = f2bf(Wl[(ks * 32 + lk * 8 + i) * 16 + ln]);
        wf[ks] = tmp.v;
    }

    float v[16];
#pragma unroll
    for (int i = 0; i < 16; ++i) v[i] = 0.f;
    if (node < nN) {
#pragma unroll
        for (int ks = 0; ks < 2; ++ks) {
            uint4 pu = *(const uint4*)(P2 + (size_t)node * 64 + ks * 32 + lk * 8);
            v[ks * 8 + 0] = lo16(pu.x); v[ks * 8 + 1] = hi16(pu.x);
            v[ks * 8 + 2] = lo16(pu.y); v[ks * 8 + 3] = hi16(pu.y);
            v[ks * 8 + 4] = lo16(pu.z); v[ks * 8 + 5] = hi16(pu.z);
            v[ks * 8 + 6] = lo16(pu.w); v[ks * 8 + 7] = hi16(pu.w);
        }
        int base = rel * N_NODES + node;
        int n = cnt[base]; if (n > BCAP) n = BCAP;
        const int* brow = bucket + (size_t)base * BCAP;
        for (int k = 0; k < n; k += 2) {
            int dn0 = brow[k];
            int dn1 = (k + 1 < n) ? brow[k + 1] : dn0;
            uint4 a0 = *(const uint4*)(Y2 + (size_t)dn0 * 64 + lk * 8);
            uint4 a1 = *(const uint4*)(Y2 + (size_t)dn0 * 64 + 32 + lk * 8);
            uint4 b0 = *(const uint4*)(Y2 + (size_t)dn1 * 64 + lk * 8);
            uint4 b1 = *(const uint4*)(Y2 + (size_t)dn1 * 64 + 32 + lk * 8);
            v[0] += lo16(a0.x); v[1] += hi16(a0.x);
            v[2] += lo16(a0.y); v[3] += hi16(a0.y);
            v[4] += lo16(a0.z); v[5] += hi16(a0.z);
            v[6] += lo16(a0.w); v[7] += hi16(a0.w);
            v[8]  += lo16(a1.x); v[9]  += hi16(a1.x);
            v[10] += lo16(a1.y); v[11] += hi16(a1.y);
            v[12] += lo16(a1.z); v[13] += hi16(a1.z);
            v[14] += lo16(a1.w); v[15] += hi16(a1.w);
            if (k + 1 < n) {
                v[0] += lo16(b0.x); v[1] += hi16(b0.x);
                v[2] += lo16(b0.y); v[3] += hi16(b0.y);
                v[4] += lo16(b0.z); v[5] += hi16(b0.z);
                v[6] += lo16(b0.w); v[7] += hi16(b0.w);
                v[8]  += lo16(b1.x); v[9]  += hi16(b1.x);
                v[10] += lo16(b1.y); v[11] += hi16(b1.y);
                v[12] += lo16(b1.z); v[13] += hi16(b1.z);
                v[14] += lo16(b1.w); v[15] += hi16(b1.w);
            }
        }
#pragma unroll
        for (int i = 0; i < 16; ++i) v[i] = fmaxf(v[i], 0.f);
    }
    union { bf16x8 bv; unsigned short u[8]; } af[2];
#pragma unroll
    for (int ks = 0; ks < 2; ++ks)
#pragma unroll
        for (int i = 0; i < 8; ++i) af[ks].u[i] = f2bf(v[ks * 8 + i]);

    f32x4 acc = (f32x4){0.f, 0.f, 0.f, 0.f};
    acc = __builtin_amdgcn_mfma_f32_16x16x32_bf16(wf[0], af[0].bv, acc, 0, 0, 0);
    acc = __builtin_amdgcn_mfma_f32_16x16x32_bf16(wf[1], af[1].bv, acc, 0, 0, 0);

    if (node < nN) {
        float4 blv = *(const float4*)(bl + lk * 4);
        float p0 = acc[0] + blv.x, p1 = acc[1] + blv.y;
        float p2 = acc[2] + blv.z, p3 = acc[3] + blv.w;
        float mx = fmaxf(fmaxf(p0, p1), fmaxf(p2, p3));
        mx = fmaxf(mx, __shfl_xor(mx, 16));
        mx = fmaxf(mx, __shfl_xor(mx, 32));
        float s = __expf(p0 - mx) + __expf(p1 - mx) + __expf(p2 - mx) + __expf(p3 - mx);
        s += __shfl_xor(s, 16);
        s += __shfl_xor(s, 32);
        float ls = logf(s) + mx;
        float4 r = make_float4(p0 - ls, p1 - ls, p2 - ls, p3 - ls);
        *(float4*)(out + (size_t)node * 16 + lk * 4) = r;
    }
}

extern "C" void kernel_launch(void* const* d_in, const int* in_sizes, int n_in,
                              void* d_out, int out_size, void* d_ws, size_t ws_size,
                              hipStream_t stream) {
    const float* x     = (const float*)d_in[0];
    const int*   ei    = (const int*)  d_in[1];   // [2, E]
    const int*   et    = (const int*)  d_in[2];   // [E]
    const float* W1    = (const float*)d_in[3];   // [5,64,64]
    const float* root1 = (const float*)d_in[4];   // [64,64]
    const float* b1    = (const float*)d_in[5];   // [64]
    const float* W2    = (const float*)d_in[6];   // [5,64,64]
    const float* root2 = (const float*)d_in[7];   // [64,64]
    const float* b2    = (const float*)d_in[8];   // [64]
    const float* Wl    = (const float*)d_in[9];   // [64,16]
    const float* bl    = (const float*)d_in[10];  // [16]
    float* out = (float*)d_out;

    const int N = N_NODES, E = N_EDGES;
    const size_t hBytes   = (size_t)N * D * sizeof(unsigned short);           // 12.8 MB
    const size_t cntBytes = ((size_t)N3 * sizeof(int) + 255) & ~(size_t)255;  // 1.2 MB
    const size_t bktBytes = ((size_t)N3 * BCAP * sizeof(int) + 255) & ~(size_t)255; // 19.2 MB

    char* ws = (char*)d_ws;
    unsigned short* Ya = (unsigned short*)ws;                 ws += hBytes;
    unsigned short* Yb = (unsigned short*)ws;                 ws += hBytes;
    unsigned short* Pa = (unsigned short*)ws;                 ws += hBytes;
    unsigned short* Pb = (unsigned short*)ws;                 ws += hBytes;
    int* cnt    = (int*)ws;                                   ws += cntBytes;
    int* bucket = (int*)ws;                                   ws += bktBytes;

    const int* src = ei;       // edge_index[0]
    const int* dst = ei + E;   // edge_index[1]

    const int finalBlocks = (N + 63) / 64;
    const int fusedBlocks = GEMM_BLOCKS + FILL_BLOCKS;

    // ---- counters must be zero before any fill slice
    hipMemsetAsync(cnt, 0, (size_t)N3 * sizeof(int), stream);

    // ---- L0: gemm0 (A = x) || fill rel 0 (needed by gemm1)
    fused0_kernel<<<fusedBlocks, 256, 0, stream>>>(
        x, src, dst, et, cnt, bucket, W1 + 0 * D * D, root1, b1, Ya, Pa, N);

    // ---- L1: gemm1 (gather rel 0) || fill rel 1 (needed by gemm2)
    gemm_fill_kernel<<<fusedBlocks, 256, 0, stream>>>(
        Pa, Ya, src, dst, et, cnt, bucket, 0, 1,
        W2 + 1 * D * D, root2, b2, Yb, Pb, N);

    // ---- L2: gemm2 (gather rel 1) || fill rel 2 (needed by final)
    gemm_fill_kernel<<<fusedBlocks, 256, 0, stream>>>(
        Pb, Yb, src, dst, et, cnt, bucket, 1, 2,
        W2 + 2 * D * D, root2, b2, Ya, Pa, N);

    // ---- final: relu(Pa + gather(rel 2, Ya)) @ Wl + bl -> log_softmax
    final_kernel<<<finalBlocks, 256, 0, stream>>>(
        Pa, Ya, cnt, bucket, 2, Wl, bl, out, N);
}

// Round 19
// 95.114 us; speedup vs baseline: 1.4499x; 1.0018x over previous
//
#include <hip/hip_runtime.h>
#include <hip/hip_bf16.h>
#include <math.h>

#define N_NODES 100000
#define N_EDGES 1000000
#define D 64
#define N3 300000          // 3 relations x N_NODES buckets
#define N3_PAD 300032      // 256B-aligned allocation, in ints
#define BCAP 16            // bucket row = exactly one 64B line
#define BM 128             // rows per gemm block
#define AST 72             // At row stride (ushorts)
#define BST 72             // Bt col stride (ushorts)
#define GEMM_BLOCKS ((N_NODES + BM - 1) / BM)     // 782
#define FILL_BLOCKS ((N_EDGES + 1023) / 1024)     // 977 (4 edges/thread)
#define CLR_BLOCKS (N3_PAD / (256 * 4))           // 293 blocks x 256 thr x int4

typedef __attribute__((ext_vector_type(8))) short bf16x8;
typedef __attribute__((ext_vector_type(4))) float f32x4;

static __device__ __forceinline__ float bf2f(unsigned short u) {
    union { unsigned int i; float f; } c; c.i = ((unsigned int)u) << 16; return c.f;
}
static __device__ __forceinline__ float lo16(unsigned int u) { return bf2f((unsigned short)(u & 0xffffu)); }
static __device__ __forceinline__ float hi16(unsigned int u) { return bf2f((unsigned short)(u >> 16)); }
static __device__ __forceinline__ unsigned short f2bf(float f) {
    union { float f; unsigned int i; } c; c.f = f;
    unsigned int i = c.i;
    return (unsigned short)((i + 0x7FFFu + ((i >> 16) & 1u)) >> 16);  // RNE
}
static __device__ __forceinline__ unsigned int pk2(float lo, float hi) {
    return (unsigned int)f2bf(lo) | ((unsigned int)f2bf(hi) << 16);
}

// ---------------------------------------------------------------------------
// clear_cnt: zero the 300k counters. R18 discovery: hipMemsetAsync of 1.2MB
// dispatches the runtime's fillBufferAligned at ~30 GB/s = 40.6us — the
// single longest stage of the whole pipeline. One int4 store per thread.
// ---------------------------------------------------------------------------
__global__ __launch_bounds__(256) void clear_cnt_kernel(int4* __restrict__ cnt4)
{
    cnt4[blockIdx.x * 256 + threadIdx.x] = make_int4(0, 0, 0, 0);
}

// ---------------------------------------------------------------------------
// fill body, 4 edges per thread, ONE relation per pass (R18: slices pipeline
// across layer launches; disjoint cnt/bucket ranges per rel).
// ---------------------------------------------------------------------------
static __device__ __forceinline__ void fill_body4(
    const int* __restrict__ src, const int* __restrict__ dst,
    const int* __restrict__ et, int* __restrict__ cnt, int* __restrict__ bucket,
    int e0, int rel)
{
    if (e0 >= N_EDGES) return;   // N_EDGES % 4 == 0
    int4 t4 = *(const int4*)(et + e0);
    int4 s4 = *(const int4*)(src + e0);
    int4 d4 = *(const int4*)(dst + e0);
    int t[4] = { t4.x, t4.y, t4.z, t4.w };
    int s[4] = { s4.x, s4.y, s4.z, s4.w };
    int d[4] = { d4.x, d4.y, d4.z, d4.w };
#pragma unroll
    for (int i = 0; i < 4; ++i) {
        if (t[i] == rel) {
            int base = rel * N_NODES + s[i];
            int pos = atomicAdd(&cnt[base], 1);
            if (pos < BCAP) bucket[(size_t)base * BCAP + pos] = d[i];
        }
    }
}

// ---------------------------------------------------------------------------
// gemm body (MFMA, swapped operands): tile [BM x 128] = A[BMx64] @ [W|root].
//   A[n] = x[n]                                (relG < 0, f32 input)
//   A[n] = relu(bf16(Pp[n]) + sum Yp[bucket])  (relG >= 0, gather fused)
// A-stage cross-pass prefetch (R17) + 4-deep Y-gather batching (R16).
// ---------------------------------------------------------------------------
static __device__ __forceinline__ void gemm_body(
    int bid,
    const float* __restrict__ Hin, const unsigned short* __restrict__ Pp,
    const unsigned short* __restrict__ Yp,
    const int* __restrict__ cnt, const int* __restrict__ bucket, int relG,
    const float* __restrict__ Wm, const float* __restrict__ Rm,
    const float* __restrict__ bias,
    unsigned short* __restrict__ Y16, unsigned short* __restrict__ P16, int nN)
{
    __shared__ unsigned short At[BM][AST];   // A rows, bf16 [row][k]
    __shared__ unsigned short Bt[128][BST];  // B cols, bf16 [col][k]
    int t = threadIdx.x;
    int n0 = bid * BM;

    // ---- stage B transposed: Bt[col][k] = bf16(B[k][col])
#pragma unroll
    for (int it = 0; it < 8; ++it) {
        int idx = t + it * 256;        // 0..2047
        int col = idx & 127;
        int k0  = (idx >> 7) * 4;
        const float* srcB = (col < 64) ? (Wm + col) : (Rm + col - 64);
        ushort4 wv;
        wv.x = f2bf(srcB[(k0 + 0) * 64]);
        wv.y = f2bf(srcB[(k0 + 1) * 64]);
        wv.z = f2bf(srcB[(k0 + 2) * 64]);
        wv.w = f2bf(srcB[(k0 + 3) * 64]);
        *(ushort4*)&Bt[col][k0] = wv;
    }

    // ---- stage A (fused gather with cross-pass prefetch), bf16 rows
    {
        int gidx = t >> 4, j = t & 15, lane = t & 63, grp = lane & 48;
        if (relG < 0) {
#pragma unroll
            for (int pass = 0; pass < 8; ++pass) {
                int rw = gidx + pass * 16;
                int node = n0 + rw;
                float4 v = make_float4(0.f, 0.f, 0.f, 0.f);
                if (node < nN) v = *(const float4*)(Hin + (size_t)node * 64 + j * 4);
                ushort4 av;
                av.x = f2bf(v.x); av.y = f2bf(v.y); av.z = f2bf(v.z); av.w = f2bf(v.w);
                *(ushort4*)&At[rw][j * 4] = av;
            }
        } else {
            // phase 1: issue all independent head loads (8x cnt, 8x brow, 8x P)
            int nn[8]; int bk[8]; ushort4 pv[8];
#pragma unroll
            for (int p = 0; p < 8; ++p) {
                int node = n0 + gidx + p * 16;
                int nodeC = (node < nN) ? node : 0;       // clamp: safe addr, result unused
                int base = relG * N_NODES + nodeC;
                nn[p] = cnt[base];
                bk[p] = bucket[(size_t)base * BCAP + j];  // unconditional
                pv[p] = *(const ushort4*)(Pp + (size_t)nodeC * 64 + j * 4);
            }
            // phase 2: per pass, gather Y rows (4-deep batched) + relu + LDS
#pragma unroll
            for (int p = 0; p < 8; ++p) {
                int rw = gidx + p * 16;
                int node = n0 + rw;
                float4 v = make_float4(0.f, 0.f, 0.f, 0.f);
                if (node < nN) {
                    v = make_float4(bf2f(pv[p].x), bf2f(pv[p].y),
                                    bf2f(pv[p].z), bf2f(pv[p].w));
                    int n = nn[p]; if (n > BCAP) n = BCAP;
                    for (int k = 0; k < n; k += 4) {
                        int i1 = (k + 1 < n) ? k + 1 : k;
                        int i2 = (k + 2 < n) ? k + 2 : k;
                        int i3 = (k + 3 < n) ? k + 3 : k;
                        int dn0 = __shfl(bk[p], grp | k);
                        int dn1 = __shfl(bk[p], grp | i1);
                        int dn2 = __shfl(bk[p], grp | i2);
                        int dn3 = __shfl(bk[p], grp | i3);
                        ushort4 u0 = *(const ushort4*)(Yp + (size_t)dn0 * 64 + j * 4);
                        ushort4 u1 = *(const ushort4*)(Yp + (size_t)dn1 * 64 + j * 4);
                        ushort4 u2 = *(const ushort4*)(Yp + (size_t)dn2 * 64 + j * 4);
                        ushort4 u3 = *(const ushort4*)(Yp + (size_t)dn3 * 64 + j * 4);
                        v.x += bf2f(u0.x); v.y += bf2f(u0.y);
                        v.z += bf2f(u0.z); v.w += bf2f(u0.w);
                        if (k + 1 < n) {
                            v.x += bf2f(u1.x); v.y += bf2f(u1.y);
                            v.z += bf2f(u1.z); v.w += bf2f(u1.w);
                        }
                        if (k + 2 < n) {
                            v.x += bf2f(u2.x); v.y += bf2f(u2.y);
                            v.z += bf2f(u2.z); v.w += bf2f(u2.w);
                        }
                        if (k + 3 < n) {
                            v.x += bf2f(u3.x); v.y += bf2f(u3.y);
                            v.z += bf2f(u3.z); v.w += bf2f(u3.w);
                        }
                    }
                    v.x = fmaxf(v.x, 0.f); v.y = fmaxf(v.y, 0.f);
                    v.z = fmaxf(v.z, 0.f); v.w = fmaxf(v.w, 0.f);
                }
                ushort4 av;
                av.x = f2bf(v.x); av.y = f2bf(v.y); av.z = f2bf(v.z); av.w = f2bf(v.w);
                *(ushort4*)&At[rw][j * 4] = av;
            }
        }
    }
    __syncthreads();

    // ---- MFMA main: wave w owns nodes w*32..w*32+31 (2 node-tiles) x 8 col-tiles
    int w  = t >> 6;
    int l  = t & 63;
    int ln = l & 15;
    int lk = l >> 4;
    f32x4 acc[2][8];
#pragma unroll
    for (int nt = 0; nt < 2; ++nt)
#pragma unroll
        for (int ct = 0; ct < 8; ++ct)
            acc[nt][ct] = (f32x4){0.f, 0.f, 0.f, 0.f};

    bf16x8 af[2][2];
#pragma unroll
    for (int nt = 0; nt < 2; ++nt)
#pragma unroll
        for (int ks = 0; ks < 2; ++ks)
            af[nt][ks] = *(const bf16x8*)&At[w * 32 + nt * 16 + ln][ks * 32 + lk * 8];

#pragma unroll
    for (int ct = 0; ct < 8; ++ct) {
        bf16x8 bf0 = *(const bf16x8*)&Bt[ct * 16 + ln][lk * 8];
        bf16x8 bf1 = *(const bf16x8*)&Bt[ct * 16 + ln][32 + lk * 8];
#pragma unroll
        for (int nt = 0; nt < 2; ++nt) {
            acc[nt][ct] = __builtin_amdgcn_mfma_f32_16x16x32_bf16(bf0, af[nt][0], acc[nt][ct], 0, 0, 0);
            acc[nt][ct] = __builtin_amdgcn_mfma_f32_16x16x32_bf16(bf1, af[nt][1], acc[nt][ct], 0, 0, 0);
        }
    }

    // ---- epilogue: lane holds node=ln, 4 consecutive cols per reg-quad; bf16 both halves
#pragma unroll
    for (int ct = 0; ct < 8; ++ct) {
        int c0 = ct * 16 + lk * 4;
#pragma unroll
        for (int nt = 0; nt < 2; ++nt) {
            int node = n0 + w * 32 + nt * 16 + ln;
            if (node >= nN) continue;
            f32x4 v = acc[nt][ct];
            if (ct < 4) {
                uint2 u;
                u.x = pk2(v[0], v[1]);
                u.y = pk2(v[2], v[3]);
                *(uint2*)(Y16 + (size_t)node * 64 + c0) = u;
            } else {
                const float4 bv = *(const float4*)(bias + (c0 - 64));
                uint2 u;
                u.x = pk2(v[0] + bv.x, v[1] + bv.y);
                u.y = pk2(v[2] + bv.z, v[3] + bv.w);
                *(uint2*)(P16 + (size_t)node * 64 + (c0 - 64)) = u;
            }
        }
    }
}

// ---------------------------------------------------------------------------
// fused0: blocks [0, GEMM_BLOCKS) run layer-0 gemm (A = x); remaining blocks
// scatter relation 0's edges (needed by gemm1).
// ---------------------------------------------------------------------------
__global__ __launch_bounds__(256) void fused0_kernel(
    const float* __restrict__ x,
    const int* __restrict__ src, const int* __restrict__ dst,
    const int* __restrict__ et, int* __restrict__ cnt, int* __restrict__ bucket,
    const float* __restrict__ Wm, const float* __restrict__ Rm,
    const float* __restrict__ bias,
    unsigned short* __restrict__ Y16, unsigned short* __restrict__ P16, int nN)
{
    if (blockIdx.x < GEMM_BLOCKS) {
        gemm_body(blockIdx.x, x, nullptr, nullptr, nullptr, nullptr, -1,
                  Wm, Rm, bias, Y16, P16, nN);
    } else {
        int e0 = ((blockIdx.x - GEMM_BLOCKS) * 256 + threadIdx.x) * 4;
        fill_body4(src, dst, et, cnt, bucket, e0, 0);
    }
}

// ---------------------------------------------------------------------------
// gemm_fill: layers 1,2 — gemm (gathering relG, filled in a previous launch)
// with relation relF's scatter fused behind it. Disjoint bucket ranges.
// ---------------------------------------------------------------------------
__global__ __launch_bounds__(256) void gemm_fill_kernel(
    const unsigned short* __restrict__ Pp, const unsigned short* __restrict__ Yp,
    const int* __restrict__ src, const int* __restrict__ dst,
    const int* __restrict__ et, int* __restrict__ cnt, int* __restrict__ bucket,
    int relG, int relF,
    const float* __restrict__ Wm, const float* __restrict__ Rm,
    const float* __restrict__ bias,
    unsigned short* __restrict__ Y16, unsigned short* __restrict__ P16, int nN)
{
    if (blockIdx.x < GEMM_BLOCKS) {
        gemm_body(blockIdx.x, nullptr, Pp, Yp, cnt, bucket, relG,
                  Wm, Rm, bias, Y16, P16, nN);
    } else {
        int e0 = ((blockIdx.x - GEMM_BLOCKS) * 256 + threadIdx.x) * 4;
        fill_body4(src, dst, et, cnt, bucket, e0, relF);
    }
}

// ---------------------------------------------------------------------------
// final (MFMA): 16 nodes/wave; row = relu(bf16 P2[n] + gather(rel2)); logits
// via swapped mfma; log_softmax with 2 shfl_xor; one float4 store per lane.
// Edge loop batched 2-deep (8 independent row-chunk loads in flight).
// ---------------------------------------------------------------------------
__global__ __launch_bounds__(256) void final_kernel(
    const unsigned short* __restrict__ P2, const unsigned short* __restrict__ Y2,
    const int* __restrict__ cnt, const int* __restrict__ bucket, int rel,
    const float* __restrict__ Wl, const float* __restrict__ bl,
    float* __restrict__ out, int nN)
{
    int t = threadIdx.x;
    int w = t >> 6, l = t & 63;
    int ln = l & 15, lk = l >> 4;
    int node = blockIdx.x * 64 + w * 16 + ln;

    bf16x8 wf[2];
#pragma unroll
    for (int ks = 0; ks < 2; ++ks) {
        union { bf16x8 v; unsigned short u[8]; } tmp;
#pragma unroll
        for (int i = 0; i < 8; ++i)
            tmp.u[i] = f2bf(Wl[(ks * 32 + lk * 8 + i) * 16 + ln]);
        wf[ks] = tmp.v;
    }

    float v[16];
#pragma unroll
    for (int i = 0; i < 16; ++i) v[i] = 0.f;
    if (node < nN) {
#pragma unroll
        for (int ks = 0; ks < 2; ++ks) {
            uint4 pu = *(const uint4*)(P2 + (size_t)node * 64 + ks * 32 + lk * 8);
            v[ks * 8 + 0] = lo16(pu.x); v[ks * 8 + 1] = hi16(pu.x);
            v[ks * 8 + 2] = lo16(pu.y); v[ks * 8 + 3] = hi16(pu.y);
            v[ks * 8 + 4] = lo16(pu.z); v[ks * 8 + 5] = hi16(pu.z);
            v[ks * 8 + 6] = lo16(pu.w); v[ks * 8 + 7] = hi16(pu.w);
        }
        int base = rel * N_NODES + node;
        int n = cnt[base]; if (n > BCAP) n = BCAP;
        const int* brow = bucket + (size_t)base * BCAP;
        for (int k = 0; k < n; k += 2) {
            int dn0 = brow[k];
            int dn1 = (k + 1 < n) ? brow[k + 1] : dn0;
            uint4 a0 = *(const uint4*)(Y2 + (size_t)dn0 * 64 + lk * 8);
            uint4 a1 = *(const uint4*)(Y2 + (size_t)dn0 * 64 + 32 + lk * 8);
            uint4 b0 = *(const uint4*)(Y2 + (size_t)dn1 * 64 + lk * 8);
            uint4 b1 = *(const uint4*)(Y2 + (size_t)dn1 * 64 + 32 + lk * 8);
            v[0] += lo16(a0.x); v[1] += hi16(a0.x);
            v[2] += lo16(a0.y); v[3] += hi16(a0.y);
            v[4] += lo16(a0.z); v[5] += hi16(a0.z);
            v[6] += lo16(a0.w); v[7] += hi16(a0.w);
            v[8]  += lo16(a1.x); v[9]  += hi16(a1.x);
            v[10] += lo16(a1.y); v[11] += hi16(a1.y);
            v[12] += lo16(a1.z); v[13] += hi16(a1.z);
            v[14] += lo16(a1.w); v[15] += hi16(a1.w);
            if (k + 1 < n) {
                v[0] += lo16(b0.x); v[1] += hi16(b0.x);
                v[2] += lo16(b0.y); v[3] += hi16(b0.y);
                v[4] += lo16(b0.z); v[5] += hi16(b0.z);
                v[6] += lo16(b0.w); v[7] += hi16(b0.w);
                v[8]  += lo16(b1.x); v[9]  += hi16(b1.x);
                v[10] += lo16(b1.y); v[11] += hi16(b1.y);
                v[12] += lo16(b1.z); v[13] += hi16(b1.z);
                v[14] += lo16(b1.w); v[15] += hi16(b1.w);
            }
        }
#pragma unroll
        for (int i = 0; i < 16; ++i) v[i] = fmaxf(v[i], 0.f);
    }
    union { bf16x8 bv; unsigned short u[8]; } af[2];
#pragma unroll
    for (int ks = 0; ks < 2; ++ks)
#pragma unroll
        for (int i = 0; i < 8; ++i) af[ks].u[i] = f2bf(v[ks * 8 + i]);

    f32x4 acc = (f32x4){0.f, 0.f, 0.f, 0.f};
    acc = __builtin_amdgcn_mfma_f32_16x16x32_bf16(wf[0], af[0].bv, acc, 0, 0, 0);
    acc = __builtin_amdgcn_mfma_f32_16x16x32_bf16(wf[1], af[1].bv, acc, 0, 0, 0);

    if (node < nN) {
        float4 blv = *(const float4*)(bl + lk * 4);
        float p0 = acc[0] + blv.x, p1 = acc[1] + blv.y;
        float p2 = acc[2] + blv.z, p3 = acc[3] + blv.w;
        float mx = fmaxf(fmaxf(p0, p1), fmaxf(p2, p3));
        mx = fmaxf(mx, __shfl_xor(mx, 16));
        mx = fmaxf(mx, __shfl_xor(mx, 32));
        float s = __expf(p0 - mx) + __expf(p1 - mx) + __expf(p2 - mx) + __expf(p3 - mx);
        s += __shfl_xor(s, 16);
        s += __shfl_xor(s, 32);
        float ls = logf(s) + mx;
        float4 r = make_float4(p0 - ls, p1 - ls, p2 - ls, p3 - ls);
        *(float4*)(out + (size_t)node * 16 + lk * 4) = r;
    }
}

extern "C" void kernel_launch(void* const* d_in, const int* in_sizes, int n_in,
                              void* d_out, int out_size, void* d_ws, size_t ws_size,
                              hipStream_t stream) {
    const float* x     = (const float*)d_in[0];
    const int*   ei    = (const int*)  d_in[1];   // [2, E]
    const int*   et    = (const int*)  d_in[2];   // [E]
    const float* W1    = (const float*)d_in[3];   // [5,64,64]
    const float* root1 = (const float*)d_in[4];   // [64,64]
    const float* b1    = (const float*)d_in[5];   // [64]
    const float* W2    = (const float*)d_in[6];   // [5,64,64]
    const float* root2 = (const float*)d_in[7];   // [64,64]
    const float* b2    = (const float*)d_in[8];   // [64]
    const float* Wl    = (const float*)d_in[9];   // [64,16]
    const float* bl    = (const float*)d_in[10];  // [16]
    float* out = (float*)d_out;

    const int N = N_NODES, E = N_EDGES;
    const size_t hBytes   = (size_t)N * D * sizeof(unsigned short);           // 12.8 MB
    const size_t cntBytes = (size_t)N3_PAD * sizeof(int);                     // 1.2 MB (aligned)
    const size_t bktBytes = ((size_t)N3 * BCAP * sizeof(int) + 255) & ~(size_t)255; // 19.2 MB

    char* ws = (char*)d_ws;
    unsigned short* Ya = (unsigned short*)ws;                 ws += hBytes;
    unsigned short* Yb = (unsigned short*)ws;                 ws += hBytes;
    unsigned short* Pa = (unsigned short*)ws;                 ws += hBytes;
    unsigned short* Pb = (unsigned short*)ws;                 ws += hBytes;
    int* cnt    = (int*)ws;                                   ws += cntBytes;
    int* bucket = (int*)ws;                                   ws += bktBytes;

    const int* src = ei;       // edge_index[0]
    const int* dst = ei + E;   // edge_index[1]

    const int finalBlocks = (N + 63) / 64;
    const int fusedBlocks = GEMM_BLOCKS + FILL_BLOCKS;

    // ---- zero counters with our own kernel (runtime memset = 40.6us @ 30GB/s)
    clear_cnt_kernel<<<CLR_BLOCKS, 256, 0, stream>>>((int4*)cnt);

    // ---- L0: gemm0 (A = x) || fill rel 0 (needed by gemm1)
    fused0_kernel<<<fusedBlocks, 256, 0, stream>>>(
        x, src, dst, et, cnt, bucket, W1 + 0 * D * D, root1, b1, Ya, Pa, N);

    // ---- L1: gemm1 (gather rel 0) || fill rel 1 (needed by gemm2)
    gemm_fill_kernel<<<fusedBlocks, 256, 0, stream>>>(
        Pa, Ya, src, dst, et, cnt, bucket, 0, 1,
        W2 + 1 * D * D, root2, b2, Yb, Pb, N);

    // ---- L2: gemm2 (gather rel 1) || fill rel 2 (needed by final)
    gemm_fill_kernel<<<fusedBlocks, 256, 0, stream>>>(
        Pb, Yb, src, dst, et, cnt, bucket, 1, 2,
        W2 + 2 * D * D, root2, b2, Ya, Pa, N);

    // ---- final: relu(Pa + gather(rel 2, Ya)) @ Wl + bl -> log_softmax
    final_kernel<<<finalBlocks, 256, 0, stream>>>(
        Pa, Ya, cnt, bucket, 2, Wl, bl, out, N);
}